// Round 5
// baseline (343.067 us; speedup 1.0000x reference)
//
#include <hip/hip_runtime.h>
#include <cstdint>

// ---------- types ----------
typedef __bf16 bf16x8 __attribute__((ext_vector_type(8)));
typedef float  floatx4 __attribute__((ext_vector_type(4)));

__device__ __forceinline__ unsigned short f2bf(float x) {
  union { float f; uint32_t u; } v; v.f = x;
  uint32_t r = (v.u + 0x7FFFu + ((v.u >> 16) & 1u)) >> 16;
  return (unsigned short)r;
}
__device__ __forceinline__ float bflo(uint32_t u) {
  union { uint32_t u; float f; } v; v.u = u << 16; return v.f;
}
__device__ __forceinline__ float bfhi(uint32_t u) {
  union { uint32_t u; float f; } v; v.u = u & 0xffff0000u; return v.f;
}
__device__ __forceinline__ float bfu(unsigned short u) {
  union { uint32_t u; float f; } v; v.u = (uint32_t)u << 16; return v.f;
}

#define QSCALE 0.18033688011f   // log2(e)/8, folded into Wq/bq at prep

// async global->LDS, 16B per lane. LDS dest must be wave-uniform base; HW adds lane*16.
__device__ __forceinline__ void async_copy16(const void* g, void* l) {
  __builtin_amdgcn_global_load_lds(
      (const __attribute__((address_space(1))) uint32_t*)g,
      (__attribute__((address_space(3))) uint32_t*)l, 16, 0, 0);
}

// ---------- bf16 GEMM: C[M,N] = A[M,K] @ Bt[N,K]^T + bias ----------
// 256x256 tile, BK=64, 8 waves (2x4). SIX single-barrier windows per
// 2-K-tile iteration (was 16 barriers): each window = {ds_reads for THIS
// window's MFMA || stage issue || 16-32 MFMA} -> barrier. Safety:
// (1) every stage targets a slot last ds_read in a strictly earlier window;
// (2) buf-switch reads (windows A/D) follow a window with per-wave vmcnt(6)
// drain + barrier. Compiler inserts fine-grained lgkmcnt for read->MFMA deps;
// asm memory clobbers pin memory ops inside windows. vmcnt never 0 in loop.
// XOR chunk-swizzle on global source + ds_read address; LDS linear.
// Requires: M,N % 256 == 0, Kper % 128 == 0, Kper >= 256.
template<int OUT_BF16, int RELU>
__global__ __launch_bounds__(512, 2)
void gemm256_kernel(const unsigned short* __restrict__ A,
                    const unsigned short* __restrict__ Bt,
                    void* __restrict__ C, const float* __restrict__ bias,
                    int M, int N, int K, int Kper) {
  // [buf][half(M/N-half)][128 rows x 64 k], 64KB each -> 128KB total, 1 block/CU
  __shared__ __align__(16) unsigned short lA[2][2][8192];
  __shared__ __align__(16) unsigned short lB[2][2][8192];
  const int tid  = threadIdx.x;
  const int wave = tid >> 6;
  const int lane = tid & 63;

  // XCD-aware swizzle (bijective since nwg % 8 == 0 for all launches here)
  const int gx = gridDim.x, gy = gridDim.y;
  const int nwg = gx * gy;
  int f = blockIdx.y * gx + blockIdx.x;
  f = (f & 7) * (nwg >> 3) + (f >> 3);
  const int m0 = (f % gy) * 256;
  const int n0 = (f / gy) * 256;
  const int kz = blockIdx.z;

  // ----- staging addressing -----
  // per thread: rows {j*64 + wave*8 + (lane>>3)} for j=0,1 of a 128-row half;
  // global k-col pre-swizzled so linear LDS dest holds chunk c at slot c^(row&7).
  const int srow = (wave << 3) + (lane >> 3);                 // 0..63
  const int scol = (((lane & 7) ^ ((lane >> 3) & 7)) << 3);   // swizzled ushort col
  const unsigned short* Ab = A  + (size_t)(m0 + srow) * K + kz * Kper + scol;
  const unsigned short* Bb = Bt + (size_t)(n0 + srow) * K + kz * Kper + scol;

  // ----- fragment addressing -----
  const int fr = lane & 15, fq = lane >> 4;
  const int wr = wave >> 2, wc = wave & 3;        // 2x4 wave grid per quadrant
  const int cc0 = ((fq ^ (lane & 7)) << 3);       // k-step 0 chunk (swizzled)
  const int cc1 = cc0 ^ 32;                       // k-step 1 chunk (= ^4 chunks)
  const int arow = (wr * 64 + fr) * 64;
  const int brow = (wc * 32 + fr) * 64;

  floatx4 acc[2][2][4][2];
  #pragma unroll
  for (int i = 0; i < 2; ++i)
    #pragma unroll
    for (int j = 0; j < 2; ++j)
      #pragma unroll
      for (int p = 0; p < 4; ++p)
        #pragma unroll
        for (int q = 0; q < 2; ++q)
          acc[i][j][p][q] = (floatx4){0.f, 0.f, 0.f, 0.f};

  bf16x8 a[4][2], b0[2][2], b1[2][2];

#define STAGE_A(b, h, kt)                                                     \
  do {                                                                        \
    const unsigned short* g_ = Ab + (size_t)((h) * 128) * K + ((size_t)(kt) << 6); \
    async_copy16(g_,                    &lA[b][h][wave << 9]);                \
    async_copy16(g_ + ((size_t)K << 6), &lA[b][h][4096 + (wave << 9)]);       \
  } while (0)
#define STAGE_B(b, h, kt)                                                     \
  do {                                                                        \
    const unsigned short* g_ = Bb + (size_t)((h) * 128) * K + ((size_t)(kt) << 6); \
    async_copy16(g_,                    &lB[b][h][wave << 9]);                \
    async_copy16(g_ + ((size_t)K << 6), &lB[b][h][4096 + (wave << 9)]);       \
  } while (0)
#define RD_A(b, h)                                                            \
  do {                                                                        \
    _Pragma("unroll")                                                         \
    for (int mt = 0; mt < 4; ++mt) {                                          \
      a[mt][0] = *(const bf16x8*)&lA[b][h][arow + mt * 1024 + cc0];           \
      a[mt][1] = *(const bf16x8*)&lA[b][h][arow + mt * 1024 + cc1];           \
    }                                                                         \
  } while (0)
#define RD_B(b, h, BB)                                                        \
  do {                                                                        \
    _Pragma("unroll")                                                         \
    for (int nt = 0; nt < 2; ++nt) {                                          \
      BB[nt][0] = *(const bf16x8*)&lB[b][h][brow + nt * 1024 + cc0];          \
      BB[nt][1] = *(const bf16x8*)&lB[b][h][brow + nt * 1024 + cc1];          \
    }                                                                         \
  } while (0)
#define MMAQ(mq, nq, BB)                                                      \
  do {                                                                        \
    __builtin_amdgcn_s_setprio(1);                                            \
    _Pragma("unroll")                                                         \
    for (int s = 0; s < 2; ++s)                                               \
      _Pragma("unroll")                                                       \
      for (int mt = 0; mt < 4; ++mt)                                          \
        _Pragma("unroll")                                                     \
        for (int nt = 0; nt < 2; ++nt)                                        \
          acc[mq][nq][mt][nt] = __builtin_amdgcn_mfma_f32_16x16x32_bf16(      \
              a[mt][s], BB[nt][s], acc[mq][nq][mt][nt], 0, 0, 0);             \
    __builtin_amdgcn_s_setprio(0);                                            \
  } while (0)
#define BARRIER() asm volatile("s_barrier" ::: "memory")
#define VMC6()    asm volatile("s_waitcnt vmcnt(6)" ::: "memory")

  const int T = Kper >> 6;   // K-tiles (even, >=4 for our shapes)

  // prologue: tile0 (all 4 halves) + tile1 (3 halves); wait all of tile0.
  STAGE_A(0, 0, 0); STAGE_B(0, 0, 0); STAGE_B(0, 1, 0); STAGE_A(0, 1, 0);
  STAGE_A(1, 0, 1); STAGE_B(1, 0, 1); STAGE_B(1, 1, 1);
  VMC6();
  BARRIER();

  // Per-thread vmcnt ledger (2 loads/stage): loop entry = 6 outstanding
  // (next odd tile's Ah0,Bh0,Bh1). A:+2=8, B:+2=10, C:+4=14 -> vmcnt(6)
  // drains buf1's 4 halves. D:+2=8, E:+2=10, F:+4=14 -> vmcnt(6) drains
  // next buf0's 4 halves. Invariant restored.
  #pragma unroll 1
  for (int it = 0; it < (T >> 1) - 1; ++it) {
    const int t0 = it << 1;
    // W_A: read buf0 a(h0)+b0+b1; stage A1h1(t0+1) (lA[1][1] last read prev W_F);
    //      MFMA (0,0)
    RD_A(0, 0); RD_B(0, 0, b0); RD_B(0, 1, b1);
    STAGE_A(1, 1, t0 + 1);
    MMAQ(0, 0, b0);
    BARRIER();
    // W_B: stage A0h0(t0+2) (last read W_A); MFMA (0,1)
    STAGE_A(0, 0, t0 + 2);
    MMAQ(0, 1, b1);
    BARRIER();
    // W_C: read a(h1); stage B0h0,B0h1(t0+2) (last read W_A);
    //      MFMA (1,0)+(1,1); drain buf1 (vmcnt(6)) then barrier
    RD_A(0, 1);
    STAGE_B(0, 0, t0 + 2); STAGE_B(0, 1, t0 + 2);
    MMAQ(1, 0, b0); MMAQ(1, 1, b1);
    VMC6();
    BARRIER();
    // W_D: read buf1 a(h0)+b0+b1 (safe: drained + barrier in W_C);
    //      stage A0h1(t0+2) (last read W_C); MFMA (0,0)
    RD_A(1, 0); RD_B(1, 0, b0); RD_B(1, 1, b1);
    STAGE_A(0, 1, t0 + 2);
    MMAQ(0, 0, b0);
    BARRIER();
    // W_E: stage A1h0(t0+3) (last read W_D); MFMA (0,1)
    STAGE_A(1, 0, t0 + 3);
    MMAQ(0, 1, b1);
    BARRIER();
    // W_F: read a(h1); stage B1h0,B1h1(t0+3) (last read W_D);
    //      MFMA (1,0)+(1,1); drain buf0(t0+2) then barrier
    RD_A(1, 1);
    STAGE_B(1, 0, t0 + 3); STAGE_B(1, 1, t0 + 3);
    MMAQ(1, 0, b0); MMAQ(1, 1, b1);
    VMC6();
    BARRIER();
  }

  // ---- peeled tail: tiles T-2 (buf0, fully drained) and T-1 (buf1) ----
  // Only A1h1 remains to stage; single vmcnt(0)+barrier before buf1 reads.
  RD_A(0, 0); RD_B(0, 0, b0); RD_B(0, 1, b1);
  STAGE_A(1, 1, T - 1);
  MMAQ(0, 0, b0);
  MMAQ(0, 1, b1);
  RD_A(0, 1);
  MMAQ(1, 0, b0); MMAQ(1, 1, b1);
  asm volatile("s_waitcnt vmcnt(0)" ::: "memory");
  BARRIER();
  RD_A(1, 0); RD_B(1, 0, b0); RD_B(1, 1, b1);
  MMAQ(0, 0, b0);
  MMAQ(0, 1, b1);
  RD_A(1, 1);
  MMAQ(1, 0, b0); MMAQ(1, 1, b1);
#undef STAGE_A
#undef STAGE_B
#undef RD_A
#undef RD_B
#undef MMAQ
#undef BARRIER
#undef VMC6

  // epilogue
  const float* bp = (kz == 0) ? bias : nullptr;
  char* Cz = (char*)C + (size_t)kz * M * N * (OUT_BF16 ? 2 : 4);
  #pragma unroll
  for (int mq = 0; mq < 2; ++mq)
    #pragma unroll
    for (int nq = 0; nq < 2; ++nq)
      #pragma unroll
      for (int mt = 0; mt < 4; ++mt)
        #pragma unroll
        for (int nt = 0; nt < 2; ++nt) {
          const int gn = n0 + nq * 128 + wc * 32 + nt * 16 + fr;
          const float bv = bp ? bp[gn] : 0.f;
          #pragma unroll
          for (int r = 0; r < 4; ++r) {
            const int gm = m0 + mq * 128 + wr * 64 + mt * 16 + fq * 4 + r;
            float v = acc[mq][nq][mt][nt][r] + bv;
            if (RELU) v = fmaxf(v, 0.f);
            if (OUT_BF16) ((unsigned short*)Cz)[(size_t)gm * N + gn] = f2bf(v);
            else          ((float*)Cz)[(size_t)gm * N + gn] = v;
          }
        }
}

// ---------- O-proj GEMM with FUSED attention-combine in the A-staging ----------
// A[gm][c] = (Opart0 + Opart1)[row(gm,c)] * invL[row(gm,c)], row = (b*16+h)*2048+q.
// M=4096,N=1024,K=1024, split-K 4 (Kper=256). bf16 out.
__global__ __launch_bounds__(256, 2)
void gemm_oproj_kernel(const unsigned short* __restrict__ Opart,
                       const float* __restrict__ invL,
                       const unsigned short* __restrict__ Bt,
                       unsigned short* __restrict__ C,
                       const float* __restrict__ bias) {
  const int K = 1024, N = 1024, M = 4096, Kper = 256;
  __shared__ __align__(16) unsigned short lA[128 * 32];
  __shared__ __align__(16) unsigned short lB[128 * 32];
  const int tid  = threadIdx.x;
  const int wave = tid >> 6;
  const int lane = tid & 63;

  const int gx = gridDim.x, gy = gridDim.y;
  int flat = blockIdx.y * gx + blockIdx.x;
  const int per = (gx * gy) >> 3;
  flat = (flat & 7) * per + (flat >> 3);
  const int sq = flat >> 6, inner = flat & 63;
  const int sqm = gy >> 3;
  const int m0 = ((sq % sqm) * 8 + (inner & 7)) * 128;
  const int n0 = ((sq / sqm) * 8 + (inner >> 3)) * 128;

  const int kz = blockIdx.z;
  const int wm = (wave >> 1) * 64;
  const int wn = (wave & 1) * 64;
  const int sa_row = lane >> 2;
  const int sa_k   = ((lane & 3) ^ ((lane >> 3) & 3)) * 8;
  const int fr = lane & 15;
  const int fq = lane >> 4;
  const int sw = (fr >> 1) & 3;

  const int r0 = (wave * 2 + 0) * 16 + sa_row;
  const int r1 = (wave * 2 + 1) * 16 + sa_row;
  const int gm0 = m0 + r0, gm1 = m0 + r1;
  const int base0 = (gm0 >> 11) * 16 * 2048 + (gm0 & 2047);   // (b*16)*2048 + q
  const int base1 = (gm1 >> 11) * 16 * 2048 + (gm1 & 2047);
  const unsigned short* B0 = Bt + (size_t)(n0 + r0) * K + kz * Kper + sa_k;
  const unsigned short* B1 = Bt + (size_t)(n0 + r1) * K + kz * Kper + sa_k;
  const int c0 = (wave * 2 + 0) * 512;
  const int c1 = (wave * 2 + 1) * 512;

  floatx4 acc[4][4];
  #pragma unroll
  for (int i = 0; i < 4; ++i)
    #pragma unroll
    for (int j = 0; j < 4; ++j)
      acc[i][j] = (floatx4){0.f, 0.f, 0.f, 0.f};

  for (int kt = 0; kt < 8; ++kt) {
    __syncthreads();
    const int kk = kz * Kper + (kt << 5) + sa_k;   // global k index (h*64 + d)
    const int h = kk >> 6, d0 = kk & 63;
    #pragma unroll
    for (int j = 0; j < 2; ++j) {
      const int base = j ? base1 : base0;
      const int cj   = j ? c1 : c0;
      const int rowi = base + h * 2048;
      const size_t idx = (size_t)rowi * 64 + d0;
      const uint4 a = *(const uint4*)(Opart + idx);
      const uint4 b = *(const uint4*)(Opart + idx + 4194304);   // + 65536*64
      const float s = invL[rowi];
      const uint32_t au[4] = {a.x, a.y, a.z, a.w};
      const uint32_t bu[4] = {b.x, b.y, b.z, b.w};
      uint32_t w[4];
      #pragma unroll
      for (int k = 0; k < 4; ++k) {
        const float lo = (bflo(au[k]) + bflo(bu[k])) * s;
        const float hi = (bfhi(au[k]) + bfhi(bu[k])) * s;
        w[k] = (uint32_t)f2bf(lo) | ((uint32_t)f2bf(hi) << 16);
      }
      uint4 wv; wv.x = w[0]; wv.y = w[1]; wv.z = w[2]; wv.w = w[3];
      *(uint4*)&lA[cj + lane * 8] = wv;
    }
    async_copy16(B0 + (kt << 5), &lB[c0]);
    async_copy16(B1 + (kt << 5), &lB[c1]);
    __syncthreads();

    bf16x8 af[4], bf[4];
    #pragma unroll
    for (int t = 0; t < 4; ++t) {
      af[t] = *(const bf16x8*)&lA[(wm + t * 16 + fr) * 32 + (fq ^ sw) * 8];
      bf[t] = *(const bf16x8*)&lB[(wn + t * 16 + fr) * 32 + (fq ^ sw) * 8];
    }
    #pragma unroll
    for (int mt = 0; mt < 4; ++mt)
      #pragma unroll
      for (int nt = 0; nt < 4; ++nt)
        acc[mt][nt] = __builtin_amdgcn_mfma_f32_16x16x32_bf16(af[mt], bf[nt], acc[mt][nt], 0, 0, 0);
  }

  const float* bp = (kz == 0) ? bias : nullptr;
  unsigned short* Cz = C + (size_t)kz * M * N;
  #pragma unroll
  for (int mt = 0; mt < 4; ++mt) {
    #pragma unroll
    for (int nt = 0; nt < 4; ++nt) {
      const int gn = n0 + wn + nt * 16 + fr;
      const float bv = bp ? bp[gn] : 0.f;
      #pragma unroll
      for (int r = 0; r < 4; ++r) {
        const int gm = m0 + wm + mt * 16 + fq * 4 + r;
        Cz[(size_t)gm * N + gn] = f2bf(acc[mt][nt][r] + bv);
      }
    }
  }
}

// ---------- repack V: QKVb bf16 [4096,3072] -> Vt [bh][d][s] ----------
// Keys permuted within each 32-tile: position p holds key
// ((p>>2)&1)*16 + (p>>3)*4 + (p&3), matching the register-resident P layout
// of the swapped QK^T (lane fq,r holds keys {kg*16 + fq*4 + r}).
__global__ __launch_bounds__(256)
void repack_v_kernel(const unsigned short* __restrict__ X,
                     unsigned short* __restrict__ Vt) {
  const int bid = blockIdx.x;                 // 1024 = b(2) x h(16) x stile(32)
  const int st = bid & 31, h = (bid >> 5) & 15, b = bid >> 9;
  const int bh = b * 16 + h;
  const int s0 = st * 64;
  const int t = threadIdx.x;
  const int sl = t >> 2;
  const int c  = (t & 3) * 16;
  __shared__ __align__(16) unsigned short vt[64][72];
  {
    const uint4* srcV = (const uint4*)(X + (size_t)(b * 2048 + s0 + sl) * 3072 + 2048 + h * 64 + c);
    uint4* dstL = (uint4*)&vt[sl][c];
    dstL[0] = srcV[0]; dstL[1] = srcV[1];
  }
  __syncthreads();
  const int d = t >> 2, cc = (t & 3) * 16;
  unsigned short tmp[16];
  #pragma unroll
  for (int j = 0; j < 16; ++j) {
    const int c64 = cc + j;
    const int grp = c64 >> 5, cw = c64 & 31;
    const int key = grp * 32 + ((cw >> 2) & 1) * 16 + ((cw >> 3) << 2) + (cw & 3);
    tmp[j] = vt[key][d];
  }
  uint4* dstV = (uint4*)(Vt + ((size_t)bh * 64 + d) * 2048 + s0 + cc);
  dstV[0] = *(uint4*)&tmp[0];
  dstV[1] = *(uint4*)&tmp[8];
}

// ---------- flash attention: barrier-free WAVE-PRIVATE LDS pipeline ----------
// Grid 512 = ksp(2) x b(2) x h(16) x qtile(8), XCD-chunked so the 8 qtiles
// sharing a (b,h,ksp) K/V land on one XCD's L2 (2MB working set / XCD).
// 4 waves x 64 q; each wave double-buffers its own K/V half-tile (4KB+4KB)
// via coalesced global_load_lds into a private LDS slice -> ZERO barriers,
// waves free-run with counted vmcnt(8). Swapped QK^T keeps P register-resident
// into PV (V key-permuted to match); row sums via ones-column MFMA.
// Writes UNNORMALIZED bf16 Opart [ksp][bh*2048+q][64] and fp32 Lpart.
__global__ __launch_bounds__(256, 2)
void flash_attn_kernel(const unsigned short* __restrict__ QKVb,
                       const unsigned short* __restrict__ Vt,
                       unsigned short* __restrict__ Opart, float* __restrict__ Lpart) {
  const int bid0 = blockIdx.x;               // 512 blocks
  const int lb = (bid0 & 7) * 64 + (bid0 >> 3);   // XCD-chunked remap (bijective)
  const int qt = lb & 7, h = (lb >> 3) & 15, b = (lb >> 7) & 1, ksp = lb >> 8;
  const int bh = b * 16 + h;
  const int wave = threadIdx.x >> 6, lane = threadIdx.x & 63;
  const int fr = lane & 15, fq = lane >> 4;

  __shared__ __align__(16) unsigned short lK[4][2][32 * 64];  // [wave][buf], 4KB each
  __shared__ __align__(16) unsigned short lV[4][2][64 * 32];  // [wave][buf], 4KB each

  const int q_base = qt * 256 + wave * 64;

  // Q fragments: 64 q per wave, resident (faithful no-transpose q view).
  bf16x8 aq[4][2];
  #pragma unroll
  for (int g = 0; g < 4; ++g) {
    const int s2 = q_base + g * 16 + fr;
    const unsigned short* qp = QKVb + (size_t)(b * 2048 + h * 128 + (s2 >> 4)) * 3072
                             + (s2 & 15) * 64 + fq * 8;
    aq[g][0] = *(const bf16x8*)qp;
    aq[g][1] = *(const bf16x8*)(qp + 32);
  }

  floatx4 o_acc[4][4], l_acc[4];
  #pragma unroll
  for (int g = 0; g < 4; ++g) {
    l_acc[g] = (floatx4){0.f, 0.f, 0.f, 0.f};
    #pragma unroll
    for (int nt = 0; nt < 4; ++nt) o_acc[g][nt] = (floatx4){0.f, 0.f, 0.f, 0.f};
  }

  const unsigned short* Kg = QKVb + 1024 + h * 64;
  const unsigned short* Vg = Vt + (size_t)bh * 64 * 2048;

  // staging addresses (wave stages its WHOLE half-tile: 4 K-rows-of-8 + 4 V-rows-of-16)
  const unsigned short* Ksrc = Kg + (size_t)(b * 2048 + (lane >> 3)) * 3072
                             + ((lane & 7) ^ (lane >> 3)) * 8;
  const unsigned short* Vsrc = Vg + (size_t)(lane >> 2) * 2048
                             + ((lane & 3) ^ ((lane >> 3) & 3)) * 8;

  auto pref = [&](int key0, int bi) {
    #pragma unroll
    for (int i = 0; i < 4; ++i)
      async_copy16(Ksrc + (size_t)(key0 + i * 8) * 3072, (char*)&lK[wave][bi][0] + i * 1024);
    #pragma unroll
    for (int i = 0; i < 4; ++i)
      async_copy16(Vsrc + (size_t)(i * 16) * 2048 + key0, (char*)&lV[wave][bi][0] + i * 1024);
  };

  const int swk = fr & 7;
  const int swv = (fr >> 1) & 3;

  bf16x8 bk[2][2], bv[4];
  bf16x8 ones;
  #pragma unroll
  for (int j = 0; j < 8; ++j) ones[j] = (__bf16)1.0f;

#define RDFRAGS(bi)                                                           \
  do {                                                                        \
    const unsigned short* LK = &lK[wave][bi][0];                              \
    const unsigned short* LV = &lV[wave][bi][0];                              \
    bk[0][0] = *(const bf16x8*)&LK[(fr) * 64      + ((0 + fq) ^ swk) * 8];    \
    bk[0][1] = *(const bf16x8*)&LK[(fr) * 64      + ((4 + fq) ^ swk) * 8];    \
    bk[1][0] = *(const bf16x8*)&LK[(16 + fr) * 64 + ((0 + fq) ^ swk) * 8];    \
    bk[1][1] = *(const bf16x8*)&LK[(16 + fr) * 64 + ((4 + fq) ^ swk) * 8];    \
    bv[0] = *(const bf16x8*)&LV[(fr) * 32      + (fq ^ swv) * 8];             \
    bv[1] = *(const bf16x8*)&LV[(16 + fr) * 32 + (fq ^ swv) * 8];             \
    bv[2] = *(const bf16x8*)&LV[(32 + fr) * 32 + (fq ^ swv) * 8];             \
    bv[3] = *(const bf16x8*)&LV[(48 + fr) * 32 + (fq ^ swv) * 8];             \
  } while (0)

#define COMPUTEH()                                                            \
  do {                                                                        \
    _Pragma("unroll")                                                         \
    for (int g = 0; g < 4; ++g) {                                             \
      floatx4 s0 = (floatx4){0.f, 0.f, 0.f, 0.f};                             \
      floatx4 s1 = (floatx4){0.f, 0.f, 0.f, 0.f};                             \
      __builtin_amdgcn_s_setprio(1);                                          \
      s0 = __builtin_amdgcn_mfma_f32_16x16x32_bf16(bk[0][0], aq[g][0], s0, 0, 0, 0); \
      s0 = __builtin_amdgcn_mfma_f32_16x16x32_bf16(bk[0][1], aq[g][1], s0, 0, 0, 0); \
      s1 = __builtin_amdgcn_mfma_f32_16x16x32_bf16(bk[1][0], aq[g][0], s1, 0, 0, 0); \
      s1 = __builtin_amdgcn_mfma_f32_16x16x32_bf16(bk[1][1], aq[g][1], s1, 0, 0, 0); \
      __builtin_amdgcn_s_setprio(0);                                          \
      float p[8];                                                             \
      _Pragma("unroll")                                                       \
      for (int r = 0; r < 4; ++r) {                                           \
        p[r]     = __builtin_amdgcn_exp2f(s0[r]);                             \
        p[4 + r] = __builtin_amdgcn_exp2f(s1[r]);                             \
      }                                                                       \
      bf16x8 ap;                                                              \
      _Pragma("unroll")                                                       \
      for (int j = 0; j < 8; ++j) ap[j] = (__bf16)p[j];                       \
      __builtin_amdgcn_s_setprio(1);                                          \
      _Pragma("unroll")                                                       \
      for (int nt = 0; nt < 4; ++nt)                                          \
        o_acc[g][nt] = __builtin_amdgcn_mfma_f32_16x16x32_bf16(ap, bv[nt], o_acc[g][nt], 0, 0, 0); \
      l_acc[g] = __builtin_amdgcn_mfma_f32_16x16x32_bf16(ap, ones, l_acc[g], 0, 0, 0); \
      __builtin_amdgcn_s_setprio(0);                                          \
    }                                                                         \
  } while (0)
#define VM8()   asm volatile("s_waitcnt vmcnt(8)" ::: "memory")
#define VM0()   asm volatile("s_waitcnt vmcnt(0)" ::: "memory")
#define LGKM0() asm volatile("s_waitcnt lgkmcnt(0)" ::: "memory")

  const int key00 = ksp * 1024;
  pref(key00, 0);                                   // 8 out
  #pragma unroll 1
  for (int hh = 0; hh < 30; hh += 2) {
    pref(key00 + (hh + 1) * 32, 1);                 // 16 out
    VM8();                                          // buf0 ready
    RDFRAGS(0); LGKM0();
    pref(key00 + (hh + 2) * 32, 0);                 // refill buf0 (reads done)
    COMPUTEH();
    VM8();                                          // buf1 ready
    RDFRAGS(1); LGKM0();
    COMPUTEH();
  }
  // tail: buf0 holds tile 30 (staged in last iter); stage 31 into buf1.
  pref(key00 + 31 * 32, 1);                         // 16 out
  VM8();
  RDFRAGS(0); LGKM0();
  COMPUTEH();
  VM0();
  RDFRAGS(1); LGKM0();
  COMPUTEH();
#undef RDFRAGS
#undef COMPUTEH
#undef VM8
#undef VM0
#undef LGKM0

  // epilogue: unnormalized bf16 partials + fp32 row sums.
  const size_t rbase = (size_t)ksp * 65536 + (size_t)bh * 2048 + q_base;
  #pragma unroll
  for (int g = 0; g < 4; ++g) {
    #pragma unroll
    for (int r = 0; r < 4; ++r)
      if (fr == 0) Lpart[rbase + g * 16 + fq * 4 + r] = l_acc[g][r];
    #pragma unroll
    for (int nt = 0; nt < 4; ++nt)
      #pragma unroll
      for (int r = 0; r < 4; ++r)
        Opart[(rbase + g * 16 + fq * 4 + r) * 64 + nt * 16 + fr] = f2bf(o_acc[g][nt][r]);
  }
}

// ---------- invL = 1/(L0+L1) ----------
__global__ __launch_bounds__(256)
void invl_kernel(const float* __restrict__ Lpart, float* __restrict__ invL) {
  const int i = blockIdx.x * 256 + threadIdx.x;   // 65536
  invL[i] = 1.f / (Lpart[i] + Lpart[i + 65536]);
}

// ---------- layernorm: LN(X + sum of NPART bf16 partials) ----------
template<int XF32, int OUTF32, int NPART>
__global__ __launch_bounds__(256)
void ln_kernel(const void* __restrict__ Xv, const unsigned short* __restrict__ R,
               const float* __restrict__ sc, const float* __restrict__ bi,
               float* __restrict__ outF, unsigned short* __restrict__ outB) {
  const int row = blockIdx.x;
  const int t = threadIdx.x;
  const size_t base = (size_t)row * 1024 + t * 4;
  float4 a;
  if (XF32) {
    a = *(const float4*)((const float*)Xv + base);
  } else {
    const ushort4 xu = *(const ushort4*)((const unsigned short*)Xv + base);
    a.x = bfu(xu.x); a.y = bfu(xu.y); a.z = bfu(xu.z); a.w = bfu(xu.w);
  }
  #pragma unroll
  for (int p = 0; p < NPART; ++p) {
    const ushort4 ru = *(const ushort4*)&R[(size_t)p * 4194304 + base];
    a.x += bfu(ru.x); a.y += bfu(ru.y); a.z += bfu(ru.z); a.w += bfu(ru.w);
  }
  float sum = (a.x + a.y) + (a.z + a.w);
  float sq  = (a.x * a.x + a.y * a.y) + (a.z * a.z + a.w * a.w);
  #pragma unroll
  for (int off = 32; off > 0; off >>= 1) {
    sum += __shfl_down(sum, off);
    sq  += __shfl_down(sq, off);
  }
  __shared__ float s1[4], s2a[4];
  const int wave = t >> 6, lane = t & 63;
  if (lane == 0) { s1[wave] = sum; s2a[wave] = sq; }
  __syncthreads();
  sum = (s1[0] + s1[1]) + (s1[2] + s1[3]);
  sq  = (s2a[0] + s2a[1]) + (s2a[2] + s2a[3]);
  const float mean = sum * (1.f / 1024.f);
  const float var  = sq * (1.f / 1024.f) - mean * mean;
  const float rstd = rsqrtf(var + 1e-5f);
  const float4 s = *(const float4*)&sc[t * 4];
  const float4 bb = *(const float4*)&bi[t * 4];
  float4 y;
  y.x = (a.x - mean) * rstd * s.x + bb.x;
  y.y = (a.y - mean) * rstd * s.y + bb.y;
  y.z = (a.z - mean) * rstd * s.z + bb.z;
  y.w = (a.w - mean) * rstd * s.w + bb.w;
  if (OUTF32) {
    *(float4*)&outF[base] = y;
  } else {
    ushort4 ob; ob.x = f2bf(y.x); ob.y = f2bf(y.y); ob.z = f2bf(y.z); ob.w = f2bf(y.w);
    *(ushort4*)&outB[base] = ob;
  }
}

// ---------- prep: weight transposes (Wq,bq scaled by log2e/8) + x cast + bias concat ----------
__global__ void prep_kernel(const float* __restrict__ Wq, const float* __restrict__ Wk,
                            const float* __restrict__ Wv, const float* __restrict__ Wo,
                            const float* __restrict__ W1, const float* __restrict__ W2,
                            unsigned short* __restrict__ Wqkvt, unsigned short* __restrict__ Wot,
                            unsigned short* __restrict__ W1t, unsigned short* __restrict__ W2t,
                            const float* __restrict__ x, unsigned short* __restrict__ xb,
                            const float* __restrict__ bq, const float* __restrict__ bk,
                            const float* __restrict__ bv, float* __restrict__ bqkv) {
  const int id = blockIdx.x;   // [0,12288) transpose; [12288,16384) cast; [16384,16396) concat
  const int tflat = threadIdx.y * 32 + threadIdx.x;
  if (id >= 16384) {
    const int i = (id - 16384) * 256 + tflat;
    if (i < 1024) bqkv[i] = bq[i] * QSCALE;
    else if (i < 2048) bqkv[i] = bk[i - 1024];
    else if (i < 3072) bqkv[i] = bv[i - 2048];
    return;
  }
  if (id >= 12288) {
    const int i = (id - 12288) * 256 + tflat;   // 1048576 float4s
    const float4 v = ((const float4*)x)[i];
    ushort4 o;
    o.x = f2bf(v.x); o.y = f2bf(v.y); o.z = f2bf(v.z); o.w = f2bf(v.w);
    ((ushort4*)xb)[i] = o;
    return;
  }
  const float* W; unsigned short* Wt; int K, N, tile;
  float scale = 1.f;
  if (id < 4096) {
    const int w = id >> 10; tile = id & 1023; K = 1024; N = 1024;
    if (w == 0)      { W = Wq; Wt = Wqkvt; scale = QSCALE; }
    else if (w == 1) { W = Wk; Wt = Wqkvt + 1024 * 1024; }
    else if (w == 2) { W = Wv; Wt = Wqkvt + 2048 * 1024; }
    else             { W = Wo; Wt = Wot; }
  } else if (id < 8192) { tile = id - 4096; W = W1; Wt = W1t; K = 1024; N = 4096; }
  else                  { tile = id - 8192; W = W2; Wt = W2t; K = 4096; N = 1024; }
  const int tilesX = N >> 5;
  const int bx = (tile & (tilesX - 1)) * 32;
  const int by = (tile / tilesX) * 32;
  __shared__ float tl[32][33];
  const int tx = threadIdx.x, ty = threadIdx.y;
  #pragma unroll
  for (int i = ty; i < 32; i += 8)
    tl[i][tx] = W[(size_t)(by + i) * N + bx + tx];
  __syncthreads();
  #pragma unroll
  for (int i = ty; i < 32; i += 8)
    Wt[(size_t)(bx + i) * K + by + tx] = f2bf(tl[tx][i] * scale);
}

// ---------- launch ----------
extern "C" void kernel_launch(void* const* d_in, const int* in_sizes, int n_in,
                              void* d_out, int out_size, void* d_ws, size_t ws_size,
                              hipStream_t stream) {
  const float* x    = (const float*)d_in[0];
  const float* Wq   = (const float*)d_in[1];
  const float* bq   = (const float*)d_in[2];
  const float* Wk   = (const float*)d_in[3];
  const float* bk   = (const float*)d_in[4];
  const float* Wv   = (const float*)d_in[5];
  const float* bv   = (const float*)d_in[6];
  const float* Wo   = (const float*)d_in[7];
  const float* bo   = (const float*)d_in[8];
  const float* ln1s = (const float*)d_in[9];
  const float* ln1b = (const float*)d_in[10];
  const float* ln2s = (const float*)d_in[11];
  const float* ln2b = (const float*)d_in[12];
  const float* W1   = (const float*)d_in[13];
  const float* b1   = (const float*)d_in[14];
  const float* W2   = (const float*)d_in[15];
  const float* b2   = (const float*)d_in[16];
  float* out = (float*)d_out;

  char* ws = (char*)d_ws;
  const size_t MB = 1u << 20;
  unsigned short* QKVb = (unsigned short*)(ws + 0);
  unsigned short* t1   = (unsigned short*)(ws + 0);
  unsigned short* ffh  = (unsigned short*)(ws + 0);
  unsigned short* Vt   = (unsigned short*)(ws + 32 * MB);
  unsigned short* ff   = (unsigned short*)(ws + 32 * MB);
  unsigned short* xb   = (unsigned short*)(ws + 48 * MB);
  unsigned short* Opart= (unsigned short*)(ws + 48 * MB);
  unsigned short* Wqkvt= (unsigned short*)(ws + 56 * MB);
  float*          Lpart= (float*)(ws + 80 * MB);
  float*          invL = (float*)(ws + 80 * MB + 512 * 1024);
  unsigned short* Wot  = (unsigned short*)(ws + 81 * MB);
  unsigned short* W1t  = (unsigned short*)(ws + 83 * MB);
  unsigned short* W2t  = (unsigned short*)(ws + 91 * MB);
  float*          bqkv = (float*)(ws + 99 * MB);
  unsigned short* x1b  = (unsigned short*)(ws + 100 * MB);

  prep_kernel<<<16396, dim3(32, 8), 0, stream>>>(Wq, Wk, Wv, Wo, W1, W2,
                                                 Wqkvt, Wot, W1t, W2t,
                                                 x, xb, bq, bk, bv, bqkv);
  // QKVb = xb @ [Wq*c|Wk|Wv] + b (bf16, 4096x3072); q-section pre-scaled by log2e/8
  gemm256_kernel<1, 0><<<dim3(12, 16, 1), 512, 0, stream>>>(xb, Wqkvt, QKVb, bqkv, 4096, 3072, 1024, 1024);
  // V transpose (32-granular key permutation matched to register-resident P)
  repack_v_kernel<<<1024, 256, 0, stream>>>(QKVb, Vt);
  // flash MFMA attention (barrier-free wave-private LDS), key-split x2 -> bf16 partials
  flash_attn_kernel<<<512, 256, 0, stream>>>(QKVb, Vt, Opart, Lpart);
  // invL = 1/(l0+l1)
  invl_kernel<<<256, 256, 0, stream>>>(Lpart, invL);
  // t1{0..3} = normalize(Opart) @ Wo + bo (bf16, split-K x4, combine fused)
  gemm_oproj_kernel<<<dim3(8, 32, 4), 256, 0, stream>>>(Opart, invL, Wot, t1, bo);
  // x1b = LN(x + sum t1) (bf16)
  ln_kernel<1, 0, 4><<<4096, 256, 0, stream>>>(x, t1, ln1s, ln1b, nullptr, x1b);
  // ffh = relu(x1b @ W1 + b1) (bf16)
  gemm256_kernel<1, 1><<<dim3(16, 16, 1), 512, 0, stream>>>(x1b, W1t, ffh, b1, 4096, 4096, 1024, 1024);
  // ff{0..3} = ffh @ W2 + b2 (bf16, split-K x4)
  gemm256_kernel<1, 0><<<dim3(4, 16, 4), 512, 0, stream>>>(ffh, W2t, ff, b2, 4096, 1024, 4096, 1024);
  // out = LN(x1b + sum ff) (fp32)
  ln_kernel<0, 1, 4><<<4096, 256, 0, stream>>>(x1b, ff, ln2s, ln2b, out, nullptr);

  (void)in_sizes; (void)n_in; (void)out_size; (void)ws_size;
}

// Round 6
// 341.581 us; speedup vs baseline: 1.0043x; 1.0043x over previous
//
#include <hip/hip_runtime.h>
#include <cstdint>

// ---------- types ----------
typedef __bf16 bf16x8 __attribute__((ext_vector_type(8)));
typedef float  floatx4 __attribute__((ext_vector_type(4)));

__device__ __forceinline__ unsigned short f2bf(float x) {
  union { float f; uint32_t u; } v; v.f = x;
  uint32_t r = (v.u + 0x7FFFu + ((v.u >> 16) & 1u)) >> 16;
  return (unsigned short)r;
}
__device__ __forceinline__ float bflo(uint32_t u) {
  union { uint32_t u; float f; } v; v.u = u << 16; return v.f;
}
__device__ __forceinline__ float bfhi(uint32_t u) {
  union { uint32_t u; float f; } v; v.u = u & 0xffff0000u; return v.f;
}
__device__ __forceinline__ float bfu(unsigned short u) {
  union { uint32_t u; float f; } v; v.u = (uint32_t)u << 16; return v.f;
}

#define QSCALE 0.18033688011f   // log2(e)/8, folded into Wq/bq at prep

// async global->LDS, 16B per lane. LDS dest must be wave-uniform base; HW adds lane*16.
__device__ __forceinline__ void async_copy16(const void* g, void* l) {
  __builtin_amdgcn_global_load_lds(
      (const __attribute__((address_space(1))) uint32_t*)g,
      (__attribute__((address_space(3))) uint32_t*)l, 16, 0, 0);
}

// ---------- bf16 GEMM: C[M,N] = A[M,K] @ Bt[N,K]^T + bias ----------
// 256x256 tile, BK=64, 8 waves (2x4), 8-phase schedule (T2+T3+T4+T5).
// ROUND-2 VERSION RESTORED (measured FF1 <= 44 us): branch-free steady loop,
// peeled final iteration, vmcnt(6) at phases 4/8 only, LGKM8 in 12-read phases.
// XOR chunk-swizzle (involution) on global source + ds_read address; LDS linear.
// Requires: M,N % 256 == 0, Kper % 128 == 0, Kper >= 256.
template<int OUT_BF16, int RELU>
__global__ __launch_bounds__(512, 2)
void gemm256_kernel(const unsigned short* __restrict__ A,
                    const unsigned short* __restrict__ Bt,
                    void* __restrict__ C, const float* __restrict__ bias,
                    int M, int N, int K, int Kper) {
  // [buf][half(M/N-half)][128 rows x 64 k], 64KB each -> 128KB total, 1 block/CU
  __shared__ __align__(16) unsigned short lA[2][2][8192];
  __shared__ __align__(16) unsigned short lB[2][2][8192];
  const int tid  = threadIdx.x;
  const int wave = tid >> 6;
  const int lane = tid & 63;

  // XCD-aware swizzle (bijective since nwg % 8 == 0 for all launches here)
  const int gx = gridDim.x, gy = gridDim.y;
  const int nwg = gx * gy;
  int f = blockIdx.y * gx + blockIdx.x;
  f = (f & 7) * (nwg >> 3) + (f >> 3);
  const int m0 = (f % gy) * 256;
  const int n0 = (f / gy) * 256;
  const int kz = blockIdx.z;

  // ----- staging addressing -----
  // per thread: rows {j*64 + wave*8 + (lane>>3)} for j=0,1 of a 128-row half;
  // global k-col pre-swizzled so linear LDS dest holds chunk c at slot c^(row&7).
  const int srow = (wave << 3) + (lane >> 3);                 // 0..63
  const int scol = (((lane & 7) ^ ((lane >> 3) & 7)) << 3);   // swizzled ushort col
  const unsigned short* Ab = A  + (size_t)(m0 + srow) * K + kz * Kper + scol;
  const unsigned short* Bb = Bt + (size_t)(n0 + srow) * K + kz * Kper + scol;

  // ----- fragment addressing -----
  const int fr = lane & 15, fq = lane >> 4;
  const int wr = wave >> 2, wc = wave & 3;        // 2x4 wave grid per quadrant
  const int cc0 = ((fq ^ (lane & 7)) << 3);       // k-step 0 chunk (swizzled)
  const int cc1 = cc0 ^ 32;                       // k-step 1 chunk (= ^4 chunks)
  const int arow = (wr * 64 + fr) * 64;
  const int brow = (wc * 32 + fr) * 64;

  floatx4 acc[2][2][4][2];
  #pragma unroll
  for (int i = 0; i < 2; ++i)
    #pragma unroll
    for (int j = 0; j < 2; ++j)
      #pragma unroll
      for (int p = 0; p < 4; ++p)
        #pragma unroll
        for (int q = 0; q < 2; ++q)
          acc[i][j][p][q] = (floatx4){0.f, 0.f, 0.f, 0.f};

  bf16x8 a[4][2], b0[2][2], b1[2][2];

#define STAGE_A(b, h, kt)                                                     \
  do {                                                                        \
    const unsigned short* g_ = Ab + (size_t)((h) * 128) * K + ((size_t)(kt) << 6); \
    async_copy16(g_,                    &lA[b][h][wave << 9]);                \
    async_copy16(g_ + ((size_t)K << 6), &lA[b][h][4096 + (wave << 9)]);       \
  } while (0)
#define STAGE_B(b, h, kt)                                                     \
  do {                                                                        \
    const unsigned short* g_ = Bb + (size_t)((h) * 128) * K + ((size_t)(kt) << 6); \
    async_copy16(g_,                    &lB[b][h][wave << 9]);                \
    async_copy16(g_ + ((size_t)K << 6), &lB[b][h][4096 + (wave << 9)]);       \
  } while (0)
#define RD_A(b, h)                                                            \
  do {                                                                        \
    _Pragma("unroll")                                                         \
    for (int mt = 0; mt < 4; ++mt) {                                          \
      a[mt][0] = *(const bf16x8*)&lA[b][h][arow + mt * 1024 + cc0];           \
      a[mt][1] = *(const bf16x8*)&lA[b][h][arow + mt * 1024 + cc1];           \
    }                                                                         \
  } while (0)
#define RD_B(b, h, BB)                                                        \
  do {                                                                        \
    _Pragma("unroll")                                                         \
    for (int nt = 0; nt < 2; ++nt) {                                          \
      BB[nt][0] = *(const bf16x8*)&lB[b][h][brow + nt * 1024 + cc0];          \
      BB[nt][1] = *(const bf16x8*)&lB[b][h][brow + nt * 1024 + cc1];          \
    }                                                                         \
  } while (0)
#define MMAQ(mq, nq, BB)                                                      \
  do {                                                                        \
    __builtin_amdgcn_s_setprio(1);                                            \
    _Pragma("unroll")                                                         \
    for (int s = 0; s < 2; ++s)                                               \
      _Pragma("unroll")                                                       \
      for (int mt = 0; mt < 4; ++mt)                                          \
        _Pragma("unroll")                                                     \
        for (int nt = 0; nt < 2; ++nt)                                        \
          acc[mq][nq][mt][nt] = __builtin_amdgcn_mfma_f32_16x16x32_bf16(      \
              a[mt][s], BB[nt][s], acc[mq][nq][mt][nt], 0, 0, 0);             \
    __builtin_amdgcn_s_setprio(0);                                            \
  } while (0)
#define BARRIER() asm volatile("s_barrier" ::: "memory")
#define LGKM0()   asm volatile("s_waitcnt lgkmcnt(0)" ::: "memory")
#define LGKM8()   asm volatile("s_waitcnt lgkmcnt(8)" ::: "memory")

  const int T = Kper >> 6;   // K-tiles (even, >=4 for our shapes)

  // prologue: tile0 (all 4 halves) + tile1 (3 halves); wait all of tile0.
  STAGE_A(0, 0, 0); STAGE_B(0, 0, 0); STAGE_B(0, 1, 0); STAGE_A(0, 1, 0);
  STAGE_A(1, 0, 1); STAGE_B(1, 0, 1); STAGE_B(1, 1, 1);
  asm volatile("s_waitcnt vmcnt(6)" ::: "memory");
  BARRIER();

  #pragma unroll 1
  for (int it = 0; it < (T >> 1) - 1; ++it) {
    const int t0 = it << 1;
    // ---- tile t0 (buf0) ----
    // ph1: quadrant (0,0); stage Ah1(t0+1) (slot dead since prev ph7)
    RD_A(0, 0); RD_B(0, 0, b0);
    STAGE_A(1, 1, t0 + 1);
    LGKM8();
    BARRIER(); LGKM0();
    MMAQ(0, 0, b0);
    BARRIER();
    // ph2: (0,1); stage Ah0(t0+2) (dead since ph1)
    RD_B(0, 1, b1);
    STAGE_A(0, 0, t0 + 2);
    BARRIER(); LGKM0();
    MMAQ(0, 1, b1);
    BARRIER();
    // ph3: (1,0); stage Bh0(t0+2) (dead since ph1)
    RD_A(0, 1);
    STAGE_B(0, 0, t0 + 2);
    BARRIER(); LGKM0();
    MMAQ(1, 0, b0);
    BARRIER();
    // ph4: (1,1); stage Bh1(t0+2) (dead since ph2); counted wait
    STAGE_B(0, 1, t0 + 2);
    asm volatile("s_waitcnt vmcnt(6)" ::: "memory");
    BARRIER();
    MMAQ(1, 1, b1);
    BARRIER();
    // ---- tile t0+1 (buf1) ----
    // ph5: (0,0); stage Ah1(t0+2) (dead since ph3)
    RD_A(1, 0); RD_B(1, 0, b0);
    STAGE_A(0, 1, t0 + 2);
    LGKM8();
    BARRIER(); LGKM0();
    MMAQ(0, 0, b0);
    BARRIER();
    // ph6: (0,1); stage Ah0(t0+3) (dead since ph5)
    RD_B(1, 1, b1);
    STAGE_A(1, 0, t0 + 3);
    BARRIER(); LGKM0();
    MMAQ(0, 1, b1);
    BARRIER();
    // ph7: (1,0); stage Bh0(t0+3) (dead since ph5)
    RD_A(1, 1);
    STAGE_B(1, 0, t0 + 3);
    BARRIER(); LGKM0();
    MMAQ(1, 0, b0);
    BARRIER();
    // ph8: (1,1); stage Bh1(t0+3) (dead since ph6); counted wait
    STAGE_B(1, 1, t0 + 3);
    asm volatile("s_waitcnt vmcnt(6)" ::: "memory");
    BARRIER();
    MMAQ(1, 1, b1);
    BARRIER();
  }

  // ---- peeled tail: tiles T-2 (buf0) and T-1 (buf1) ----
  RD_A(0, 0); RD_B(0, 0, b0);
  STAGE_A(1, 1, T - 1);
  MMAQ(0, 0, b0);
  RD_B(0, 1, b1);
  MMAQ(0, 1, b1);
  RD_A(0, 1);
  MMAQ(1, 0, b0);
  MMAQ(1, 1, b1);
  asm volatile("s_waitcnt vmcnt(0)" ::: "memory");
  BARRIER();
  RD_A(1, 0); RD_B(1, 0, b0);
  MMAQ(0, 0, b0);
  RD_B(1, 1, b1);
  MMAQ(0, 1, b1);
  RD_A(1, 1);
  MMAQ(1, 0, b0);
  MMAQ(1, 1, b1);
#undef STAGE_A
#undef STAGE_B
#undef RD_A
#undef RD_B
#undef MMAQ
#undef BARRIER
#undef LGKM0
#undef LGKM8

  // epilogue
  const float* bp = (kz == 0) ? bias : nullptr;
  char* Cz = (char*)C + (size_t)kz * M * N * (OUT_BF16 ? 2 : 4);
  #pragma unroll
  for (int mq = 0; mq < 2; ++mq)
    #pragma unroll
    for (int nq = 0; nq < 2; ++nq)
      #pragma unroll
      for (int mt = 0; mt < 4; ++mt)
        #pragma unroll
        for (int nt = 0; nt < 2; ++nt) {
          const int gn = n0 + nq * 128 + wc * 32 + nt * 16 + fr;
          const float bv = bp ? bp[gn] : 0.f;
          #pragma unroll
          for (int r = 0; r < 4; ++r) {
            const int gm = m0 + mq * 128 + wr * 64 + mt * 16 + fq * 4 + r;
            float v = acc[mq][nq][mt][nt][r] + bv;
            if (RELU) v = fmaxf(v, 0.f);
            if (OUT_BF16) ((unsigned short*)Cz)[(size_t)gm * N + gn] = f2bf(v);
            else          ((float*)Cz)[(size_t)gm * N + gn] = v;
          }
        }
}

// ---------- O-proj GEMM with FUSED attention-combine in the A-staging ----------
// A[gm][c] = (Opart0 + Opart1)[row(gm,c)] * invL[row(gm,c)], row = (b*16+h)*2048+q.
// M=4096,N=1024,K=1024, split-K 2 (Kper=512). bf16 out.
__global__ __launch_bounds__(256, 2)
void gemm_oproj_kernel(const unsigned short* __restrict__ Opart,
                       const float* __restrict__ invL,
                       const unsigned short* __restrict__ Bt,
                       unsigned short* __restrict__ C,
                       const float* __restrict__ bias) {
  const int K = 1024, N = 1024, M = 4096, Kper = 512;
  __shared__ __align__(16) unsigned short lA[128 * 32];
  __shared__ __align__(16) unsigned short lB[128 * 32];
  const int tid  = threadIdx.x;
  const int wave = tid >> 6;
  const int lane = tid & 63;

  const int gx = gridDim.x, gy = gridDim.y;
  int flat = blockIdx.y * gx + blockIdx.x;
  const int per = (gx * gy) >> 3;
  flat = (flat & 7) * per + (flat >> 3);
  const int sq = flat >> 6, inner = flat & 63;
  const int sqm = gy >> 3;
  const int m0 = ((sq % sqm) * 8 + (inner & 7)) * 128;
  const int n0 = ((sq / sqm) * 8 + (inner >> 3)) * 128;

  const int kz = blockIdx.z;
  const int wm = (wave >> 1) * 64;
  const int wn = (wave & 1) * 64;
  const int sa_row = lane >> 2;
  const int sa_k   = ((lane & 3) ^ ((lane >> 3) & 3)) * 8;
  const int fr = lane & 15;
  const int fq = lane >> 4;
  const int sw = (fr >> 1) & 3;

  const int r0 = (wave * 2 + 0) * 16 + sa_row;
  const int r1 = (wave * 2 + 1) * 16 + sa_row;
  const int gm0 = m0 + r0, gm1 = m0 + r1;
  const int base0 = (gm0 >> 11) * 16 * 2048 + (gm0 & 2047);   // (b*16)*2048 + q
  const int base1 = (gm1 >> 11) * 16 * 2048 + (gm1 & 2047);
  const unsigned short* B0 = Bt + (size_t)(n0 + r0) * K + kz * Kper + sa_k;
  const unsigned short* B1 = Bt + (size_t)(n0 + r1) * K + kz * Kper + sa_k;
  const int c0 = (wave * 2 + 0) * 512;
  const int c1 = (wave * 2 + 1) * 512;

  floatx4 acc[4][4];
  #pragma unroll
  for (int i = 0; i < 4; ++i)
    #pragma unroll
    for (int j = 0; j < 4; ++j)
      acc[i][j] = (floatx4){0.f, 0.f, 0.f, 0.f};

  for (int kt = 0; kt < 16; ++kt) {
    __syncthreads();
    const int kk = kz * Kper + (kt << 5) + sa_k;   // global k index (h*64 + d)
    const int h = kk >> 6, d0 = kk & 63;
    #pragma unroll
    for (int j = 0; j < 2; ++j) {
      const int base = j ? base1 : base0;
      const int cj   = j ? c1 : c0;
      const int rowi = base + h * 2048;
      const size_t idx = (size_t)rowi * 64 + d0;
      const uint4 a = *(const uint4*)(Opart + idx);
      const uint4 b = *(const uint4*)(Opart + idx + 4194304);   // + 65536*64
      const float s = invL[rowi];
      const uint32_t au[4] = {a.x, a.y, a.z, a.w};
      const uint32_t bu[4] = {b.x, b.y, b.z, b.w};
      uint32_t w[4];
      #pragma unroll
      for (int k = 0; k < 4; ++k) {
        const float lo = (bflo(au[k]) + bflo(bu[k])) * s;
        const float hi = (bfhi(au[k]) + bfhi(bu[k])) * s;
        w[k] = (uint32_t)f2bf(lo) | ((uint32_t)f2bf(hi) << 16);
      }
      uint4 wv; wv.x = w[0]; wv.y = w[1]; wv.z = w[2]; wv.w = w[3];
      *(uint4*)&lA[cj + lane * 8] = wv;
    }
    async_copy16(B0 + (kt << 5), &lB[c0]);
    async_copy16(B1 + (kt << 5), &lB[c1]);
    __syncthreads();

    bf16x8 af[4], bf[4];
    #pragma unroll
    for (int t = 0; t < 4; ++t) {
      af[t] = *(const bf16x8*)&lA[(wm + t * 16 + fr) * 32 + (fq ^ sw) * 8];
      bf[t] = *(const bf16x8*)&lB[(wn + t * 16 + fr) * 32 + (fq ^ sw) * 8];
    }
    #pragma unroll
    for (int mt = 0; mt < 4; ++mt)
      #pragma unroll
      for (int nt = 0; nt < 4; ++nt)
        acc[mt][nt] = __builtin_amdgcn_mfma_f32_16x16x32_bf16(af[mt], bf[nt], acc[mt][nt], 0, 0, 0);
  }

  const float* bp = (kz == 0) ? bias : nullptr;
  unsigned short* Cz = C + (size_t)kz * M * N;
  #pragma unroll
  for (int mt = 0; mt < 4; ++mt) {
    #pragma unroll
    for (int nt = 0; nt < 4; ++nt) {
      const int gn = n0 + wn + nt * 16 + fr;
      const float bv = bp ? bp[gn] : 0.f;
      #pragma unroll
      for (int r = 0; r < 4; ++r) {
        const int gm = m0 + wm + mt * 16 + fq * 4 + r;
        Cz[(size_t)gm * N + gn] = f2bf(acc[mt][nt][r] + bv);
      }
    }
  }
}

// ---------- repack V: QKVb bf16 [4096,3072] -> Vt [bh][d][s] ----------
// Keys permuted within each 32-tile: position p holds key
// ((p>>2)&1)*16 + (p>>3)*4 + (p&3), matching the register-resident P layout
// of the swapped QK^T (lane fq,r holds keys {kg*16 + fq*4 + r}).
__global__ __launch_bounds__(256)
void repack_v_kernel(const unsigned short* __restrict__ X,
                     unsigned short* __restrict__ Vt) {
  const int bid = blockIdx.x;                 // 1024 = b(2) x h(16) x stile(32)
  const int st = bid & 31, h = (bid >> 5) & 15, b = bid >> 9;
  const int bh = b * 16 + h;
  const int s0 = st * 64;
  const int t = threadIdx.x;
  const int sl = t >> 2;
  const int c  = (t & 3) * 16;
  __shared__ __align__(16) unsigned short vt[64][72];
  {
    const uint4* srcV = (const uint4*)(X + (size_t)(b * 2048 + s0 + sl) * 3072 + 2048 + h * 64 + c);
    uint4* dstL = (uint4*)&vt[sl][c];
    dstL[0] = srcV[0]; dstL[1] = srcV[1];
  }
  __syncthreads();
  const int d = t >> 2, cc = (t & 3) * 16;
  unsigned short tmp[16];
  #pragma unroll
  for (int j = 0; j < 16; ++j) {
    const int c64 = cc + j;
    const int grp = c64 >> 5, cw = c64 & 31;
    const int key = grp * 32 + ((cw >> 2) & 1) * 16 + ((cw >> 3) << 2) + (cw & 3);
    tmp[j] = vt[key][d];
  }
  uint4* dstV = (uint4*)(Vt + ((size_t)bh * 64 + d) * 2048 + s0 + cc);
  dstV[0] = *(uint4*)&tmp[0];
  dstV[1] = *(uint4*)&tmp[8];
}

// ---------- flash attention: barrier-free WAVE-PRIVATE LDS pipeline ----------
// Grid 512 = ksp(2) x b(2) x h(16) x qtile(8), XCD-chunked so the 8 qtiles
// sharing a (b,h,ksp) K/V land on one XCD's L2 (2MB working set / XCD).
// 4 waves x 64 q; each wave double-buffers its own K/V half-tile (4KB+4KB)
// via coalesced global_load_lds into a private LDS slice -> ZERO barriers,
// waves free-run with counted vmcnt(8). Swapped QK^T keeps P register-resident
// into PV (V key-permuted to match); row sums via ones-column MFMA.
// Writes UNNORMALIZED bf16 Opart [ksp][bh*2048+q][64] and fp32 Lpart.
__global__ __launch_bounds__(256, 2)
void flash_attn_kernel(const unsigned short* __restrict__ QKVb,
                       const unsigned short* __restrict__ Vt,
                       unsigned short* __restrict__ Opart, float* __restrict__ Lpart) {
  const int bid0 = blockIdx.x;               // 512 blocks
  const int lb = (bid0 & 7) * 64 + (bid0 >> 3);   // XCD-chunked remap (bijective)
  const int qt = lb & 7, h = (lb >> 3) & 15, b = (lb >> 7) & 1, ksp = lb >> 8;
  const int bh = b * 16 + h;
  const int wave = threadIdx.x >> 6, lane = threadIdx.x & 63;
  const int fr = lane & 15, fq = lane >> 4;

  __shared__ __align__(16) unsigned short lK[4][2][32 * 64];  // [wave][buf], 4KB each
  __shared__ __align__(16) unsigned short lV[4][2][64 * 32];  // [wave][buf], 4KB each

  const int q_base = qt * 256 + wave * 64;

  // Q fragments: 64 q per wave, resident (faithful no-transpose q view).
  bf16x8 aq[4][2];
  #pragma unroll
  for (int g = 0; g < 4; ++g) {
    const int s2 = q_base + g * 16 + fr;
    const unsigned short* qp = QKVb + (size_t)(b * 2048 + h * 128 + (s2 >> 4)) * 3072
                             + (s2 & 15) * 64 + fq * 8;
    aq[g][0] = *(const bf16x8*)qp;
    aq[g][1] = *(const bf16x8*)(qp + 32);
  }

  floatx4 o_acc[4][4], l_acc[4];
  #pragma unroll
  for (int g = 0; g < 4; ++g) {
    l_acc[g] = (floatx4){0.f, 0.f, 0.f, 0.f};
    #pragma unroll
    for (int nt = 0; nt < 4; ++nt) o_acc[g][nt] = (floatx4){0.f, 0.f, 0.f, 0.f};
  }

  const unsigned short* Kg = QKVb + 1024 + h * 64;
  const unsigned short* Vg = Vt + (size_t)bh * 64 * 2048;

  // staging addresses (wave stages its WHOLE half-tile: 4 K-rows-of-8 + 4 V-rows-of-16)
  const unsigned short* Ksrc = Kg + (size_t)(b * 2048 + (lane >> 3)) * 3072
                             + ((lane & 7) ^ (lane >> 3)) * 8;
  const unsigned short* Vsrc = Vg + (size_t)(lane >> 2) * 2048
                             + ((lane & 3) ^ ((lane >> 3) & 3)) * 8;

  auto pref = [&](int key0, int bi) {
    #pragma unroll
    for (int i = 0; i < 4; ++i)
      async_copy16(Ksrc + (size_t)(key0 + i * 8) * 3072, (char*)&lK[wave][bi][0] + i * 1024);
    #pragma unroll
    for (int i = 0; i < 4; ++i)
      async_copy16(Vsrc + (size_t)(i * 16) * 2048 + key0, (char*)&lV[wave][bi][0] + i * 1024);
  };

  const int swk = fr & 7;
  const int swv = (fr >> 1) & 3;

  bf16x8 bk[2][2], bv[4];
  bf16x8 ones;
  #pragma unroll
  for (int j = 0; j < 8; ++j) ones[j] = (__bf16)1.0f;

#define RDFRAGS(bi)                                                           \
  do {                                                                        \
    const unsigned short* LK = &lK[wave][bi][0];                              \
    const unsigned short* LV = &lV[wave][bi][0];                              \
    bk[0][0] = *(const bf16x8*)&LK[(fr) * 64      + ((0 + fq) ^ swk) * 8];    \
    bk[0][1] = *(const bf16x8*)&LK[(fr) * 64      + ((4 + fq) ^ swk) * 8];    \
    bk[1][0] = *(const bf16x8*)&LK[(16 + fr) * 64 + ((0 + fq) ^ swk) * 8];    \
    bk[1][1] = *(const bf16x8*)&LK[(16 + fr) * 64 + ((4 + fq) ^ swk) * 8];    \
    bv[0] = *(const bf16x8*)&LV[(fr) * 32      + (fq ^ swv) * 8];             \
    bv[1] = *(const bf16x8*)&LV[(16 + fr) * 32 + (fq ^ swv) * 8];             \
    bv[2] = *(const bf16x8*)&LV[(32 + fr) * 32 + (fq ^ swv) * 8];             \
    bv[3] = *(const bf16x8*)&LV[(48 + fr) * 32 + (fq ^ swv) * 8];             \
  } while (0)

#define COMPUTEH()                                                            \
  do {                                                                        \
    _Pragma("unroll")                                                         \
    for (int g = 0; g < 4; ++g) {                                             \
      floatx4 s0 = (floatx4){0.f, 0.f, 0.f, 0.f};                             \
      floatx4 s1 = (floatx4){0.f, 0.f, 0.f, 0.f};                             \
      __builtin_amdgcn_s_setprio(1);                                          \
      s0 = __builtin_amdgcn_mfma_f32_16x16x32_bf16(bk[0][0], aq[g][0], s0, 0, 0, 0); \
      s0 = __builtin_amdgcn_mfma_f32_16x16x32_bf16(bk[0][1], aq[g][1], s0, 0, 0, 0); \
      s1 = __builtin_amdgcn_mfma_f32_16x16x32_bf16(bk[1][0], aq[g][0], s1, 0, 0, 0); \
      s1 = __builtin_amdgcn_mfma_f32_16x16x32_bf16(bk[1][1], aq[g][1], s1, 0, 0, 0); \
      __builtin_amdgcn_s_setprio(0);                                          \
      float p[8];                                                             \
      _Pragma("unroll")                                                       \
      for (int r = 0; r < 4; ++r) {                                           \
        p[r]     = __builtin_amdgcn_exp2f(s0[r]);                             \
        p[4 + r] = __builtin_amdgcn_exp2f(s1[r]);                             \
      }                                                                       \
      bf16x8 ap;                                                              \
      _Pragma("unroll")                                                       \
      for (int j = 0; j < 8; ++j) ap[j] = (__bf16)p[j];                       \
      __builtin_amdgcn_s_setprio(1);                                          \
      _Pragma("unroll")                                                       \
      for (int nt = 0; nt < 4; ++nt)                                          \
        o_acc[g][nt] = __builtin_amdgcn_mfma_f32_16x16x32_bf16(ap, bv[nt], o_acc[g][nt], 0, 0, 0); \
      l_acc[g] = __builtin_amdgcn_mfma_f32_16x16x32_bf16(ap, ones, l_acc[g], 0, 0, 0); \
      __builtin_amdgcn_s_setprio(0);                                          \
    }                                                                         \
  } while (0)
#define VM8()   asm volatile("s_waitcnt vmcnt(8)" ::: "memory")
#define VM0()   asm volatile("s_waitcnt vmcnt(0)" ::: "memory")
#define LGKM0() asm volatile("s_waitcnt lgkmcnt(0)" ::: "memory")

  const int key00 = ksp * 1024;
  pref(key00, 0);                                   // 8 out
  #pragma unroll 1
  for (int hh = 0; hh < 30; hh += 2) {
    pref(key00 + (hh + 1) * 32, 1);                 // 16 out
    VM8();                                          // buf0 ready
    RDFRAGS(0); LGKM0();
    pref(key00 + (hh + 2) * 32, 0);                 // refill buf0 (reads done)
    COMPUTEH();
    VM8();                                          // buf1 ready
    RDFRAGS(1); LGKM0();
    COMPUTEH();
  }
  // tail: buf0 holds tile 30 (staged in last iter); stage 31 into buf1.
  pref(key00 + 31 * 32, 1);                         // 16 out
  VM8();
  RDFRAGS(0); LGKM0();
  COMPUTEH();
  VM0();
  RDFRAGS(1); LGKM0();
  COMPUTEH();
#undef RDFRAGS
#undef COMPUTEH
#undef VM8
#undef VM0
#undef LGKM0

  // epilogue: unnormalized bf16 partials + fp32 row sums.
  const size_t rbase = (size_t)ksp * 65536 + (size_t)bh * 2048 + q_base;
  #pragma unroll
  for (int g = 0; g < 4; ++g) {
    #pragma unroll
    for (int r = 0; r < 4; ++r)
      if (fr == 0) Lpart[rbase + g * 16 + fq * 4 + r] = l_acc[g][r];
    #pragma unroll
    for (int nt = 0; nt < 4; ++nt)
      #pragma unroll
      for (int r = 0; r < 4; ++r)
        Opart[(rbase + g * 16 + fq * 4 + r) * 64 + nt * 16 + fr] = f2bf(o_acc[g][nt][r]);
  }
}

// ---------- invL = 1/(L0+L1) ----------
__global__ __launch_bounds__(256)
void invl_kernel(const float* __restrict__ Lpart, float* __restrict__ invL) {
  const int i = blockIdx.x * 256 + threadIdx.x;   // 65536
  invL[i] = 1.f / (Lpart[i] + Lpart[i + 65536]);
}

// ---------- layernorm: LN(X + sum of NPART bf16 partials) ----------
template<int XF32, int OUTF32, int NPART>
__global__ __launch_bounds__(256)
void ln_kernel(const void* __restrict__ Xv, const unsigned short* __restrict__ R,
               const float* __restrict__ sc, const float* __restrict__ bi,
               float* __restrict__ outF, unsigned short* __restrict__ outB) {
  const int row = blockIdx.x;
  const int t = threadIdx.x;
  const size_t base = (size_t)row * 1024 + t * 4;
  float4 a;
  if (XF32) {
    a = *(const float4*)((const float*)Xv + base);
  } else {
    const ushort4 xu = *(const ushort4*)((const unsigned short*)Xv + base);
    a.x = bfu(xu.x); a.y = bfu(xu.y); a.z = bfu(xu.z); a.w = bfu(xu.w);
  }
  #pragma unroll
  for (int p = 0; p < NPART; ++p) {
    const ushort4 ru = *(const ushort4*)&R[(size_t)p * 4194304 + base];
    a.x += bfu(ru.x); a.y += bfu(ru.y); a.z += bfu(ru.z); a.w += bfu(ru.w);
  }
  float sum = (a.x + a.y) + (a.z + a.w);
  float sq  = (a.x * a.x + a.y * a.y) + (a.z * a.z + a.w * a.w);
  #pragma unroll
  for (int off = 32; off > 0; off >>= 1) {
    sum += __shfl_down(sum, off);
    sq  += __shfl_down(sq, off);
  }
  __shared__ float s1[4], s2a[4];
  const int wave = t >> 6, lane = t & 63;
  if (lane == 0) { s1[wave] = sum; s2a[wave] = sq; }
  __syncthreads();
  sum = (s1[0] + s1[1]) + (s1[2] + s1[3]);
  sq  = (s2a[0] + s2a[1]) + (s2a[2] + s2a[3]);
  const float mean = sum * (1.f / 1024.f);
  const float var  = sq * (1.f / 1024.f) - mean * mean;
  const float rstd = rsqrtf(var + 1e-5f);
  const float4 s = *(const float4*)&sc[t * 4];
  const float4 bb = *(const float4*)&bi[t * 4];
  float4 y;
  y.x = (a.x - mean) * rstd * s.x + bb.x;
  y.y = (a.y - mean) * rstd * s.y + bb.y;
  y.z = (a.z - mean) * rstd * s.z + bb.z;
  y.w = (a.w - mean) * rstd * s.w + bb.w;
  if (OUTF32) {
    *(float4*)&outF[base] = y;
  } else {
    ushort4 ob; ob.x = f2bf(y.x); ob.y = f2bf(y.y); ob.z = f2bf(y.z); ob.w = f2bf(y.w);
    *(ushort4*)&outB[base] = ob;
  }
}

// ---------- prep: weight transposes (Wq,bq scaled by log2e/8) + x cast + bias concat ----------
__global__ void prep_kernel(const float* __restrict__ Wq, const float* __restrict__ Wk,
                            const float* __restrict__ Wv, const float* __restrict__ Wo,
                            const float* __restrict__ W1, const float* __restrict__ W2,
                            unsigned short* __restrict__ Wqkvt, unsigned short* __restrict__ Wot,
                            unsigned short* __restrict__ W1t, unsigned short* __restrict__ W2t,
                            const float* __restrict__ x, unsigned short* __restrict__ xb,
                            const float* __restrict__ bq, const float* __restrict__ bk,
                            const float* __restrict__ bv, float* __restrict__ bqkv) {
  const int id = blockIdx.x;   // [0,12288) transpose; [12288,16384) cast; [16384,16396) concat
  const int tflat = threadIdx.y * 32 + threadIdx.x;
  if (id >= 16384) {
    const int i = (id - 16384) * 256 + tflat;
    if (i < 1024) bqkv[i] = bq[i] * QSCALE;
    else if (i < 2048) bqkv[i] = bk[i - 1024];
    else if (i < 3072) bqkv[i] = bv[i - 2048];
    return;
  }
  if (id >= 12288) {
    const int i = (id - 12288) * 256 + tflat;   // 1048576 float4s
    const float4 v = ((const float4*)x)[i];
    ushort4 o;
    o.x = f2bf(v.x); o.y = f2bf(v.y); o.z = f2bf(v.z); o.w = f2bf(v.w);
    ((ushort4*)xb)[i] = o;
    return;
  }
  const float* W; unsigned short* Wt; int K, N, tile;
  float scale = 1.f;
  if (id < 4096) {
    const int w = id >> 10; tile = id & 1023; K = 1024; N = 1024;
    if (w == 0)      { W = Wq; Wt = Wqkvt; scale = QSCALE; }
    else if (w == 1) { W = Wk; Wt = Wqkvt + 1024 * 1024; }
    else if (w == 2) { W = Wv; Wt = Wqkvt + 2048 * 1024; }
    else             { W = Wo; Wt = Wot; }
  } else if (id < 8192) { tile = id - 4096; W = W1; Wt = W1t; K = 1024; N = 4096; }
  else                  { tile = id - 8192; W = W2; Wt = W2t; K = 4096; N = 1024; }
  const int tilesX = N >> 5;
  const int bx = (tile & (tilesX - 1)) * 32;
  const int by = (tile / tilesX) * 32;
  __shared__ float tl[32][33];
  const int tx = threadIdx.x, ty = threadIdx.y;
  #pragma unroll
  for (int i = ty; i < 32; i += 8)
    tl[i][tx] = W[(size_t)(by + i) * N + bx + tx];
  __syncthreads();
  #pragma unroll
  for (int i = ty; i < 32; i += 8)
    Wt[(size_t)(bx + i) * K + by + tx] = f2bf(tl[tx][i] * scale);
}

// ---------- launch ----------
extern "C" void kernel_launch(void* const* d_in, const int* in_sizes, int n_in,
                              void* d_out, int out_size, void* d_ws, size_t ws_size,
                              hipStream_t stream) {
  const float* x    = (const float*)d_in[0];
  const float* Wq   = (const float*)d_in[1];
  const float* bq   = (const float*)d_in[2];
  const float* Wk   = (const float*)d_in[3];
  const float* bk   = (const float*)d_in[4];
  const float* Wv   = (const float*)d_in[5];
  const float* bv   = (const float*)d_in[6];
  const float* Wo   = (const float*)d_in[7];
  const float* bo   = (const float*)d_in[8];
  const float* ln1s = (const float*)d_in[9];
  const float* ln1b = (const float*)d_in[10];
  const float* ln2s = (const float*)d_in[11];
  const float* ln2b = (const float*)d_in[12];
  const float* W1   = (const float*)d_in[13];
  const float* b1   = (const float*)d_in[14];
  const float* W2   = (const float*)d_in[15];
  const float* b2   = (const float*)d_in[16];
  float* out = (float*)d_out;

  char* ws = (char*)d_ws;
  const size_t MB = 1u << 20;
  unsigned short* QKVb = (unsigned short*)(ws + 0);
  unsigned short* t1   = (unsigned short*)(ws + 0);
  unsigned short* ffh  = (unsigned short*)(ws + 0);
  unsigned short* Vt   = (unsigned short*)(ws + 32 * MB);
  unsigned short* ff   = (unsigned short*)(ws + 32 * MB);
  unsigned short* xb   = (unsigned short*)(ws + 48 * MB);
  unsigned short* Opart= (unsigned short*)(ws + 48 * MB);
  unsigned short* Wqkvt= (unsigned short*)(ws + 56 * MB);
  float*          Lpart= (float*)(ws + 80 * MB);
  float*          invL = (float*)(ws + 80 * MB + 512 * 1024);
  unsigned short* Wot  = (unsigned short*)(ws + 81 * MB);
  unsigned short* W1t  = (unsigned short*)(ws + 83 * MB);
  unsigned short* W2t  = (unsigned short*)(ws + 91 * MB);
  float*          bqkv = (float*)(ws + 99 * MB);
  unsigned short* x1b  = (unsigned short*)(ws + 100 * MB);

  prep_kernel<<<16396, dim3(32, 8), 0, stream>>>(Wq, Wk, Wv, Wo, W1, W2,
                                                 Wqkvt, Wot, W1t, W2t,
                                                 x, xb, bq, bk, bv, bqkv);
  // QKVb = xb @ [Wq*c|Wk|Wv] + b (bf16, 4096x3072); q-section pre-scaled by log2e/8
  gemm256_kernel<1, 0><<<dim3(12, 16, 1), 512, 0, stream>>>(xb, Wqkvt, QKVb, bqkv, 4096, 3072, 1024, 1024);
  // V transpose (32-granular key permutation matched to register-resident P)
  repack_v_kernel<<<1024, 256, 0, stream>>>(QKVb, Vt);
  // flash MFMA attention (barrier-free wave-private LDS), key-split x2 -> bf16 partials
  flash_attn_kernel<<<512, 256, 0, stream>>>(QKVb, Vt, Opart, Lpart);
  // invL = 1/(l0+l1)
  invl_kernel<<<256, 256, 0, stream>>>(Lpart, invL);
  // t1{0..1} = normalize(Opart) @ Wo + bo (bf16, split-K x2, combine fused)
  gemm_oproj_kernel<<<dim3(8, 32, 2), 256, 0, stream>>>(Opart, invL, Wot, t1, bo);
  // x1b = LN(x + sum t1) (bf16)
  ln_kernel<1, 0, 2><<<4096, 256, 0, stream>>>(x, t1, ln1s, ln1b, nullptr, x1b);
  // ffh = relu(x1b @ W1 + b1) (bf16)
  gemm256_kernel<1, 1><<<dim3(16, 16, 1), 512, 0, stream>>>(x1b, W1t, ffh, b1, 4096, 4096, 1024, 1024);
  // ff{0..3} = ffh @ W2 + b2 (bf16, split-K x4)
  gemm256_kernel<1, 0><<<dim3(4, 16, 4), 512, 0, stream>>>(ffh, W2t, ff, b2, 4096, 1024, 4096, 1024);
  // out = LN(x1b + sum ff) (fp32)
  ln_kernel<0, 1, 4><<<4096, 256, 0, stream>>>(x1b, ff, ln2s, ln2b, out, nullptr);

  (void)in_sizes; (void)n_in; (void)out_size; (void)ws_size;
}

// Round 7
// 338.791 us; speedup vs baseline: 1.0126x; 1.0082x over previous
//
#include <hip/hip_runtime.h>
#include <cstdint>

// ---------- types ----------
typedef __bf16 bf16x8 __attribute__((ext_vector_type(8)));
typedef float  floatx4 __attribute__((ext_vector_type(4)));

__device__ __forceinline__ unsigned short f2bf(float x) {
  union { float f; uint32_t u; } v; v.f = x;
  uint32_t r = (v.u + 0x7FFFu + ((v.u >> 16) & 1u)) >> 16;
  return (unsigned short)r;
}
__device__ __forceinline__ float bflo(uint32_t u) {
  union { uint32_t u; float f; } v; v.u = u << 16; return v.f;
}
__device__ __forceinline__ float bfhi(uint32_t u) {
  union { uint32_t u; float f; } v; v.u = u & 0xffff0000u; return v.f;
}
__device__ __forceinline__ float bfu(unsigned short u) {
  union { uint32_t u; float f; } v; v.u = (uint32_t)u << 16; return v.f;
}

#define QSCALE 0.18033688011f   // log2(e)/8, folded into Wq/bq at prep

// async global->LDS, 16B per lane. LDS dest must be wave-uniform base; HW adds lane*16.
__device__ __forceinline__ void async_copy16(const void* g, void* l) {
  __builtin_amdgcn_global_load_lds(
      (const __attribute__((address_space(1))) uint32_t*)g,
      (__attribute__((address_space(3))) uint32_t*)l, 16, 0, 0);
}

// ---------- bf16 GEMM: C[M,N] = A[M,K] @ Bt[N,K]^T + bias ----------
// 256x256 tile, BK=64, 8 waves (2x4), 8-phase schedule (T2+T3+T4+T5).
// Branch-free steady loop, peeled final iteration, vmcnt(6) at phases 4/8.
// THIS ROUND: __builtin_amdgcn_s_barrier() instead of asm s_barrier+"memory"
// clobber (matches the verified template/HK) so the scheduler may move
// hazard-free ds_reads/address setup across phase edges; counted waits stay asm.
// XOR chunk-swizzle (involution) on global source + ds_read address; LDS linear.
// Requires: M,N % 256 == 0, Kper % 128 == 0, Kper >= 256.
template<int OUT_BF16, int RELU>
__global__ __launch_bounds__(512, 2)
void gemm256_kernel(const unsigned short* __restrict__ A,
                    const unsigned short* __restrict__ Bt,
                    void* __restrict__ C, const float* __restrict__ bias,
                    int M, int N, int K, int Kper) {
  // [buf][half(M/N-half)][128 rows x 64 k], 64KB each -> 128KB total, 1 block/CU
  __shared__ __align__(16) unsigned short lA[2][2][8192];
  __shared__ __align__(16) unsigned short lB[2][2][8192];
  const int tid  = threadIdx.x;
  const int wave = tid >> 6;
  const int lane = tid & 63;

  // XCD-aware swizzle (bijective since nwg % 8 == 0 for all launches here)
  const int gx = gridDim.x, gy = gridDim.y;
  const int nwg = gx * gy;
  int f = blockIdx.y * gx + blockIdx.x;
  f = (f & 7) * (nwg >> 3) + (f >> 3);
  const int m0 = (f % gy) * 256;
  const int n0 = (f / gy) * 256;
  const int kz = blockIdx.z;

  // ----- staging addressing -----
  // per thread: rows {j*64 + wave*8 + (lane>>3)} for j=0,1 of a 128-row half;
  // global k-col pre-swizzled so linear LDS dest holds chunk c at slot c^(row&7).
  const int srow = (wave << 3) + (lane >> 3);                 // 0..63
  const int scol = (((lane & 7) ^ ((lane >> 3) & 7)) << 3);   // swizzled ushort col
  const unsigned short* Ab = A  + (size_t)(m0 + srow) * K + kz * Kper + scol;
  const unsigned short* Bb = Bt + (size_t)(n0 + srow) * K + kz * Kper + scol;

  // ----- fragment addressing -----
  const int fr = lane & 15, fq = lane >> 4;
  const int wr = wave >> 2, wc = wave & 3;        // 2x4 wave grid per quadrant
  const int cc0 = ((fq ^ (lane & 7)) << 3);       // k-step 0 chunk (swizzled)
  const int cc1 = cc0 ^ 32;                       // k-step 1 chunk (= ^4 chunks)
  const int arow = (wr * 64 + fr) * 64;
  const int brow = (wc * 32 + fr) * 64;

  floatx4 acc[2][2][4][2];
  #pragma unroll
  for (int i = 0; i < 2; ++i)
    #pragma unroll
    for (int j = 0; j < 2; ++j)
      #pragma unroll
      for (int p = 0; p < 4; ++p)
        #pragma unroll
        for (int q = 0; q < 2; ++q)
          acc[i][j][p][q] = (floatx4){0.f, 0.f, 0.f, 0.f};

  bf16x8 a[4][2], b0[2][2], b1[2][2];

#define STAGE_A(b, h, kt)                                                     \
  do {                                                                        \
    const unsigned short* g_ = Ab + (size_t)((h) * 128) * K + ((size_t)(kt) << 6); \
    async_copy16(g_,                    &lA[b][h][wave << 9]);                \
    async_copy16(g_ + ((size_t)K << 6), &lA[b][h][4096 + (wave << 9)]);       \
  } while (0)
#define STAGE_B(b, h, kt)                                                     \
  do {                                                                        \
    const unsigned short* g_ = Bb + (size_t)((h) * 128) * K + ((size_t)(kt) << 6); \
    async_copy16(g_,                    &lB[b][h][wave << 9]);                \
    async_copy16(g_ + ((size_t)K << 6), &lB[b][h][4096 + (wave << 9)]);       \
  } while (0)
#define RD_A(b, h)                                                            \
  do {                                                                        \
    _Pragma("unroll")                                                         \
    for (int mt = 0; mt < 4; ++mt) {                                          \
      a[mt][0] = *(const bf16x8*)&lA[b][h][arow + mt * 1024 + cc0];           \
      a[mt][1] = *(const bf16x8*)&lA[b][h][arow + mt * 1024 + cc1];           \
    }                                                                         \
  } while (0)
#define RD_B(b, h, BB)                                                        \
  do {                                                                        \
    _Pragma("unroll")                                                         \
    for (int nt = 0; nt < 2; ++nt) {                                          \
      BB[nt][0] = *(const bf16x8*)&lB[b][h][brow + nt * 1024 + cc0];          \
      BB[nt][1] = *(const bf16x8*)&lB[b][h][brow + nt * 1024 + cc1];          \
    }                                                                         \
  } while (0)
#define MMAQ(mq, nq, BB)                                                      \
  do {                                                                        \
    __builtin_amdgcn_s_setprio(1);                                            \
    _Pragma("unroll")                                                         \
    for (int s = 0; s < 2; ++s)                                               \
      _Pragma("unroll")                                                       \
      for (int mt = 0; mt < 4; ++mt)                                          \
        _Pragma("unroll")                                                     \
        for (int nt = 0; nt < 2; ++nt)                                        \
          acc[mq][nq][mt][nt] = __builtin_amdgcn_mfma_f32_16x16x32_bf16(      \
              a[mt][s], BB[nt][s], acc[mq][nq][mt][nt], 0, 0, 0);             \
    __builtin_amdgcn_s_setprio(0);                                            \
  } while (0)
#define BARRIER() __builtin_amdgcn_s_barrier()
#define LGKM0()   asm volatile("s_waitcnt lgkmcnt(0)" ::: "memory")
#define LGKM8()   asm volatile("s_waitcnt lgkmcnt(8)" ::: "memory")

  const int T = Kper >> 6;   // K-tiles (even, >=4 for our shapes)

  // prologue: tile0 (all 4 halves) + tile1 (3 halves); wait all of tile0.
  STAGE_A(0, 0, 0); STAGE_B(0, 0, 0); STAGE_B(0, 1, 0); STAGE_A(0, 1, 0);
  STAGE_A(1, 0, 1); STAGE_B(1, 0, 1); STAGE_B(1, 1, 1);
  asm volatile("s_waitcnt vmcnt(6)" ::: "memory");
  BARRIER();

  #pragma unroll 1
  for (int it = 0; it < (T >> 1) - 1; ++it) {
    const int t0 = it << 1;
    // ---- tile t0 (buf0) ----
    // ph1: quadrant (0,0); stage Ah1(t0+1) (slot dead since prev ph7)
    RD_A(0, 0); RD_B(0, 0, b0);
    STAGE_A(1, 1, t0 + 1);
    LGKM8();
    BARRIER(); LGKM0();
    MMAQ(0, 0, b0);
    BARRIER();
    // ph2: (0,1); stage Ah0(t0+2) (dead since ph1)
    RD_B(0, 1, b1);
    STAGE_A(0, 0, t0 + 2);
    BARRIER(); LGKM0();
    MMAQ(0, 1, b1);
    BARRIER();
    // ph3: (1,0); stage Bh0(t0+2) (dead since ph1)
    RD_A(0, 1);
    STAGE_B(0, 0, t0 + 2);
    BARRIER(); LGKM0();
    MMAQ(1, 0, b0);
    BARRIER();
    // ph4: (1,1); stage Bh1(t0+2) (dead since ph2); counted wait
    STAGE_B(0, 1, t0 + 2);
    asm volatile("s_waitcnt vmcnt(6)" ::: "memory");
    BARRIER();
    MMAQ(1, 1, b1);
    BARRIER();
    // ---- tile t0+1 (buf1) ----
    // ph5: (0,0); stage Ah1(t0+2) (dead since ph3)
    RD_A(1, 0); RD_B(1, 0, b0);
    STAGE_A(0, 1, t0 + 2);
    LGKM8();
    BARRIER(); LGKM0();
    MMAQ(0, 0, b0);
    BARRIER();
    // ph6: (0,1); stage Ah0(t0+3) (dead since ph5)
    RD_B(1, 1, b1);
    STAGE_A(1, 0, t0 + 3);
    BARRIER(); LGKM0();
    MMAQ(0, 1, b1);
    BARRIER();
    // ph7: (1,0); stage Bh0(t0+3) (dead since ph5)
    RD_A(1, 1);
    STAGE_B(1, 0, t0 + 3);
    BARRIER(); LGKM0();
    MMAQ(1, 0, b0);
    BARRIER();
    // ph8: (1,1); stage Bh1(t0+3) (dead since ph6); counted wait
    STAGE_B(1, 1, t0 + 3);
    asm volatile("s_waitcnt vmcnt(6)" ::: "memory");
    BARRIER();
    MMAQ(1, 1, b1);
    BARRIER();
  }

  // ---- peeled tail: tiles T-2 (buf0) and T-1 (buf1) ----
  RD_A(0, 0); RD_B(0, 0, b0);
  STAGE_A(1, 1, T - 1);
  MMAQ(0, 0, b0);
  RD_B(0, 1, b1);
  MMAQ(0, 1, b1);
  RD_A(0, 1);
  MMAQ(1, 0, b0);
  MMAQ(1, 1, b1);
  asm volatile("s_waitcnt vmcnt(0)" ::: "memory");
  BARRIER();
  RD_A(1, 0); RD_B(1, 0, b0);
  MMAQ(0, 0, b0);
  RD_B(1, 1, b1);
  MMAQ(0, 1, b1);
  RD_A(1, 1);
  MMAQ(1, 0, b0);
  MMAQ(1, 1, b1);
#undef STAGE_A
#undef STAGE_B
#undef RD_A
#undef RD_B
#undef MMAQ
#undef BARRIER
#undef LGKM0
#undef LGKM8

  // epilogue
  const float* bp = (kz == 0) ? bias : nullptr;
  char* Cz = (char*)C + (size_t)kz * M * N * (OUT_BF16 ? 2 : 4);
  #pragma unroll
  for (int mq = 0; mq < 2; ++mq)
    #pragma unroll
    for (int nq = 0; nq < 2; ++nq)
      #pragma unroll
      for (int mt = 0; mt < 4; ++mt)
        #pragma unroll
        for (int nt = 0; nt < 2; ++nt) {
          const int gn = n0 + nq * 128 + wc * 32 + nt * 16 + fr;
          const float bv = bp ? bp[gn] : 0.f;
          #pragma unroll
          for (int r = 0; r < 4; ++r) {
            const int gm = m0 + mq * 128 + wr * 64 + mt * 16 + fq * 4 + r;
            float v = acc[mq][nq][mt][nt][r] + bv;
            if (RELU) v = fmaxf(v, 0.f);
            if (OUT_BF16) ((unsigned short*)Cz)[(size_t)gm * N + gn] = f2bf(v);
            else          ((float*)Cz)[(size_t)gm * N + gn] = v;
          }
        }
}

// ---------- O-proj GEMM with FUSED attention-combine + invL in the A-staging ----------
// A[gm][c] = (Opart0 + Opart1)[row(gm,c)] * rcp(L0+L1)[row(gm,c)], row = (b*16+h)*2048+q.
// M=4096,N=1024,K=1024, split-K 2 (Kper=512). bf16 out.
__global__ __launch_bounds__(256, 2)
void gemm_oproj_kernel(const unsigned short* __restrict__ Opart,
                       const float* __restrict__ Lpart,
                       const unsigned short* __restrict__ Bt,
                       unsigned short* __restrict__ C,
                       const float* __restrict__ bias) {
  const int K = 1024, N = 1024, M = 4096, Kper = 512;
  __shared__ __align__(16) unsigned short lA[128 * 32];
  __shared__ __align__(16) unsigned short lB[128 * 32];
  const int tid  = threadIdx.x;
  const int wave = tid >> 6;
  const int lane = tid & 63;

  const int gx = gridDim.x, gy = gridDim.y;
  int flat = blockIdx.y * gx + blockIdx.x;
  const int per = (gx * gy) >> 3;
  flat = (flat & 7) * per + (flat >> 3);
  const int sq = flat >> 6, inner = flat & 63;
  const int sqm = gy >> 3;
  const int m0 = ((sq % sqm) * 8 + (inner & 7)) * 128;
  const int n0 = ((sq / sqm) * 8 + (inner >> 3)) * 128;

  const int kz = blockIdx.z;
  const int wm = (wave >> 1) * 64;
  const int wn = (wave & 1) * 64;
  const int sa_row = lane >> 2;
  const int sa_k   = ((lane & 3) ^ ((lane >> 3) & 3)) * 8;
  const int fr = lane & 15;
  const int fq = lane >> 4;
  const int sw = (fr >> 1) & 3;

  const int r0 = (wave * 2 + 0) * 16 + sa_row;
  const int r1 = (wave * 2 + 1) * 16 + sa_row;
  const int gm0 = m0 + r0, gm1 = m0 + r1;
  const int base0 = (gm0 >> 11) * 16 * 2048 + (gm0 & 2047);   // (b*16)*2048 + q
  const int base1 = (gm1 >> 11) * 16 * 2048 + (gm1 & 2047);
  const unsigned short* B0 = Bt + (size_t)(n0 + r0) * K + kz * Kper + sa_k;
  const unsigned short* B1 = Bt + (size_t)(n0 + r1) * K + kz * Kper + sa_k;
  const int c0 = (wave * 2 + 0) * 512;
  const int c1 = (wave * 2 + 1) * 512;

  floatx4 acc[4][4];
  #pragma unroll
  for (int i = 0; i < 4; ++i)
    #pragma unroll
    for (int j = 0; j < 4; ++j)
      acc[i][j] = (floatx4){0.f, 0.f, 0.f, 0.f};

  for (int kt = 0; kt < 16; ++kt) {
    __syncthreads();
    const int kk = kz * Kper + (kt << 5) + sa_k;   // global k index (h*64 + d)
    const int h = kk >> 6, d0 = kk & 63;
    #pragma unroll
    for (int j = 0; j < 2; ++j) {
      const int base = j ? base1 : base0;
      const int cj   = j ? c1 : c0;
      const int rowi = base + h * 2048;
      const size_t idx = (size_t)rowi * 64 + d0;
      const uint4 a = *(const uint4*)(Opart + idx);
      const uint4 b = *(const uint4*)(Opart + idx + 4194304);   // + 65536*64
      const float s = __builtin_amdgcn_rcpf(Lpart[rowi] + Lpart[rowi + 65536]);
      const uint32_t au[4] = {a.x, a.y, a.z, a.w};
      const uint32_t bu[4] = {b.x, b.y, b.z, b.w};
      uint32_t w[4];
      #pragma unroll
      for (int k = 0; k < 4; ++k) {
        const float lo = (bflo(au[k]) + bflo(bu[k])) * s;
        const float hi = (bfhi(au[k]) + bfhi(bu[k])) * s;
        w[k] = (uint32_t)f2bf(lo) | ((uint32_t)f2bf(hi) << 16);
      }
      uint4 wv; wv.x = w[0]; wv.y = w[1]; wv.z = w[2]; wv.w = w[3];
      *(uint4*)&lA[cj + lane * 8] = wv;
    }
    async_copy16(B0 + (kt << 5), &lB[c0]);
    async_copy16(B1 + (kt << 5), &lB[c1]);
    __syncthreads();

    bf16x8 af[4], bf[4];
    #pragma unroll
    for (int t = 0; t < 4; ++t) {
      af[t] = *(const bf16x8*)&lA[(wm + t * 16 + fr) * 32 + (fq ^ sw) * 8];
      bf[t] = *(const bf16x8*)&lB[(wn + t * 16 + fr) * 32 + (fq ^ sw) * 8];
    }
    #pragma unroll
    for (int mt = 0; mt < 4; ++mt)
      #pragma unroll
      for (int nt = 0; nt < 4; ++nt)
        acc[mt][nt] = __builtin_amdgcn_mfma_f32_16x16x32_bf16(af[mt], bf[nt], acc[mt][nt], 0, 0, 0);
  }

  const float* bp = (kz == 0) ? bias : nullptr;
  unsigned short* Cz = C + (size_t)kz * M * N;
  #pragma unroll
  for (int mt = 0; mt < 4; ++mt) {
    #pragma unroll
    for (int nt = 0; nt < 4; ++nt) {
      const int gn = n0 + wn + nt * 16 + fr;
      const float bv = bp ? bp[gn] : 0.f;
      #pragma unroll
      for (int r = 0; r < 4; ++r) {
        const int gm = m0 + wm + mt * 16 + fq * 4 + r;
        Cz[(size_t)gm * N + gn] = f2bf(acc[mt][nt][r] + bv);
      }
    }
  }
}

// ---------- repack V: QKVb bf16 [4096,3072] -> Vt [bh][d][s] ----------
// Keys permuted within each 32-tile: position p holds key
// ((p>>2)&1)*16 + (p>>3)*4 + (p&3), matching the register-resident P layout
// of the swapped QK^T (lane fq,r holds keys {kg*16 + fq*4 + r}).
__global__ __launch_bounds__(256)
void repack_v_kernel(const unsigned short* __restrict__ X,
                     unsigned short* __restrict__ Vt) {
  const int bid = blockIdx.x;                 // 1024 = b(2) x h(16) x stile(32)
  const int st = bid & 31, h = (bid >> 5) & 15, b = bid >> 9;
  const int bh = b * 16 + h;
  const int s0 = st * 64;
  const int t = threadIdx.x;
  const int sl = t >> 2;
  const int c  = (t & 3) * 16;
  __shared__ __align__(16) unsigned short vt[64][72];
  {
    const uint4* srcV = (const uint4*)(X + (size_t)(b * 2048 + s0 + sl) * 3072 + 2048 + h * 64 + c);
    uint4* dstL = (uint4*)&vt[sl][c];
    dstL[0] = srcV[0]; dstL[1] = srcV[1];
  }
  __syncthreads();
  const int d = t >> 2, cc = (t & 3) * 16;
  unsigned short tmp[16];
  #pragma unroll
  for (int j = 0; j < 16; ++j) {
    const int c64 = cc + j;
    const int grp = c64 >> 5, cw = c64 & 31;
    const int key = grp * 32 + ((cw >> 2) & 1) * 16 + ((cw >> 3) << 2) + (cw & 3);
    tmp[j] = vt[key][d];
  }
  uint4* dstV = (uint4*)(Vt + ((size_t)bh * 64 + d) * 2048 + s0 + cc);
  dstV[0] = *(uint4*)&tmp[0];
  dstV[1] = *(uint4*)&tmp[8];
}

// ---------- flash attention: barrier-free WAVE-PRIVATE LDS pipeline ----------
// Grid 512 = ksp(2) x b(2) x h(16) x qtile(8), XCD-chunked so the 8 qtiles
// sharing a (b,h,ksp) K/V land on one XCD's L2 (2MB working set / XCD).
// 4 waves x 64 q; each wave double-buffers its own K/V half-tile (4KB+4KB)
// via coalesced global_load_lds into a private LDS slice -> ZERO barriers,
// waves free-run with counted vmcnt(8). Swapped QK^T keeps P register-resident
// into PV (V key-permuted to match); row sums via ones-column MFMA.
// Writes UNNORMALIZED bf16 Opart [ksp][bh*2048+q][64] and fp32 Lpart.
__global__ __launch_bounds__(256, 2)
void flash_attn_kernel(const unsigned short* __restrict__ QKVb,
                       const unsigned short* __restrict__ Vt,
                       unsigned short* __restrict__ Opart, float* __restrict__ Lpart) {
  const int bid0 = blockIdx.x;               // 512 blocks
  const int lb = (bid0 & 7) * 64 + (bid0 >> 3);   // XCD-chunked remap (bijective)
  const int qt = lb & 7, h = (lb >> 3) & 15, b = (lb >> 7) & 1, ksp = lb >> 8;
  const int bh = b * 16 + h;
  const int wave = threadIdx.x >> 6, lane = threadIdx.x & 63;
  const int fr = lane & 15, fq = lane >> 4;

  __shared__ __align__(16) unsigned short lK[4][2][32 * 64];  // [wave][buf], 4KB each
  __shared__ __align__(16) unsigned short lV[4][2][64 * 32];  // [wave][buf], 4KB each

  const int q_base = qt * 256 + wave * 64;

  // Q fragments: 64 q per wave, resident (faithful no-transpose q view).
  bf16x8 aq[4][2];
  #pragma unroll
  for (int g = 0; g < 4; ++g) {
    const int s2 = q_base + g * 16 + fr;
    const unsigned short* qp = QKVb + (size_t)(b * 2048 + h * 128 + (s2 >> 4)) * 3072
                             + (s2 & 15) * 64 + fq * 8;
    aq[g][0] = *(const bf16x8*)qp;
    aq[g][1] = *(const bf16x8*)(qp + 32);
  }

  floatx4 o_acc[4][4], l_acc[4];
  #pragma unroll
  for (int g = 0; g < 4; ++g) {
    l_acc[g] = (floatx4){0.f, 0.f, 0.f, 0.f};
    #pragma unroll
    for (int nt = 0; nt < 4; ++nt) o_acc[g][nt] = (floatx4){0.f, 0.f, 0.f, 0.f};
  }

  const unsigned short* Kg = QKVb + 1024 + h * 64;
  const unsigned short* Vg = Vt + (size_t)bh * 64 * 2048;

  // staging addresses (wave stages its WHOLE half-tile: 4 K-rows-of-8 + 4 V-rows-of-16)
  const unsigned short* Ksrc = Kg + (size_t)(b * 2048 + (lane >> 3)) * 3072
                             + ((lane & 7) ^ (lane >> 3)) * 8;
  const unsigned short* Vsrc = Vg + (size_t)(lane >> 2) * 2048
                             + ((lane & 3) ^ ((lane >> 3) & 3)) * 8;

  auto pref = [&](int key0, int bi) {
    #pragma unroll
    for (int i = 0; i < 4; ++i)
      async_copy16(Ksrc + (size_t)(key0 + i * 8) * 3072, (char*)&lK[wave][bi][0] + i * 1024);
    #pragma unroll
    for (int i = 0; i < 4; ++i)
      async_copy16(Vsrc + (size_t)(i * 16) * 2048 + key0, (char*)&lV[wave][bi][0] + i * 1024);
  };

  const int swk = fr & 7;
  const int swv = (fr >> 1) & 3;

  bf16x8 bk[2][2], bv[4];
  bf16x8 ones;
  #pragma unroll
  for (int j = 0; j < 8; ++j) ones[j] = (__bf16)1.0f;

#define RDFRAGS(bi)                                                           \
  do {                                                                        \
    const unsigned short* LK = &lK[wave][bi][0];                              \
    const unsigned short* LV = &lV[wave][bi][0];                              \
    bk[0][0] = *(const bf16x8*)&LK[(fr) * 64      + ((0 + fq) ^ swk) * 8];    \
    bk[0][1] = *(const bf16x8*)&LK[(fr) * 64      + ((4 + fq) ^ swk) * 8];    \
    bk[1][0] = *(const bf16x8*)&LK[(16 + fr) * 64 + ((0 + fq) ^ swk) * 8];    \
    bk[1][1] = *(const bf16x8*)&LK[(16 + fr) * 64 + ((4 + fq) ^ swk) * 8];    \
    bv[0] = *(const bf16x8*)&LV[(fr) * 32      + (fq ^ swv) * 8];             \
    bv[1] = *(const bf16x8*)&LV[(16 + fr) * 32 + (fq ^ swv) * 8];             \
    bv[2] = *(const bf16x8*)&LV[(32 + fr) * 32 + (fq ^ swv) * 8];             \
    bv[3] = *(const bf16x8*)&LV[(48 + fr) * 32 + (fq ^ swv) * 8];             \
  } while (0)

#define COMPUTEH()                                                            \
  do {                                                                        \
    _Pragma("unroll")                                                         \
    for (int g = 0; g < 4; ++g) {                                             \
      floatx4 s0 = (floatx4){0.f, 0.f, 0.f, 0.f};                             \
      floatx4 s1 = (floatx4){0.f, 0.f, 0.f, 0.f};                             \
      __builtin_amdgcn_s_setprio(1);                                          \
      s0 = __builtin_amdgcn_mfma_f32_16x16x32_bf16(bk[0][0], aq[g][0], s0, 0, 0, 0); \
      s0 = __builtin_amdgcn_mfma_f32_16x16x32_bf16(bk[0][1], aq[g][1], s0, 0, 0, 0); \
      s1 = __builtin_amdgcn_mfma_f32_16x16x32_bf16(bk[1][0], aq[g][0], s1, 0, 0, 0); \
      s1 = __builtin_amdgcn_mfma_f32_16x16x32_bf16(bk[1][1], aq[g][1], s1, 0, 0, 0); \
      __builtin_amdgcn_s_setprio(0);                                          \
      float p[8];                                                             \
      _Pragma("unroll")                                                       \
      for (int r = 0; r < 4; ++r) {                                           \
        p[r]     = __builtin_amdgcn_exp2f(s0[r]);                             \
        p[4 + r] = __builtin_amdgcn_exp2f(s1[r]);                             \
      }                                                                       \
      bf16x8 ap;                                                              \
      _Pragma("unroll")                                                       \
      for (int j = 0; j < 8; ++j) ap[j] = (__bf16)p[j];                       \
      __builtin_amdgcn_s_setprio(1);                                          \
      _Pragma("unroll")                                                       \
      for (int nt = 0; nt < 4; ++nt)                                          \
        o_acc[g][nt] = __builtin_amdgcn_mfma_f32_16x16x32_bf16(ap, bv[nt], o_acc[g][nt], 0, 0, 0); \
      l_acc[g] = __builtin_amdgcn_mfma_f32_16x16x32_bf16(ap, ones, l_acc[g], 0, 0, 0); \
      __builtin_amdgcn_s_setprio(0);                                          \
    }                                                                         \
  } while (0)
#define VM8()   asm volatile("s_waitcnt vmcnt(8)" ::: "memory")
#define VM0()   asm volatile("s_waitcnt vmcnt(0)" ::: "memory")
#define LGKM0() asm volatile("s_waitcnt lgkmcnt(0)" ::: "memory")

  const int key00 = ksp * 1024;
  pref(key00, 0);                                   // 8 out
  #pragma unroll 1
  for (int hh = 0; hh < 30; hh += 2) {
    pref(key00 + (hh + 1) * 32, 1);                 // 16 out
    VM8();                                          // buf0 ready
    RDFRAGS(0); LGKM0();
    pref(key00 + (hh + 2) * 32, 0);                 // refill buf0 (reads done)
    COMPUTEH();
    VM8();                                          // buf1 ready
    RDFRAGS(1); LGKM0();
    COMPUTEH();
  }
  // tail: buf0 holds tile 30 (staged in last iter); stage 31 into buf1.
  pref(key00 + 31 * 32, 1);                         // 16 out
  VM8();
  RDFRAGS(0); LGKM0();
  COMPUTEH();
  VM0();
  RDFRAGS(1); LGKM0();
  COMPUTEH();
#undef RDFRAGS
#undef COMPUTEH
#undef VM8
#undef VM0
#undef LGKM0

  // epilogue: unnormalized bf16 partials + fp32 row sums.
  const size_t rbase = (size_t)ksp * 65536 + (size_t)bh * 2048 + q_base;
  #pragma unroll
  for (int g = 0; g < 4; ++g) {
    #pragma unroll
    for (int r = 0; r < 4; ++r)
      if (fr == 0) Lpart[rbase + g * 16 + fq * 4 + r] = l_acc[g][r];
    #pragma unroll
    for (int nt = 0; nt < 4; ++nt)
      #pragma unroll
      for (int r = 0; r < 4; ++r)
        Opart[(rbase + g * 16 + fq * 4 + r) * 64 + nt * 16 + fr] = f2bf(o_acc[g][nt][r]);
  }
}

// ---------- layernorm: LN(X + sum of NPART bf16 partials) ----------
template<int XF32, int OUTF32, int NPART>
__global__ __launch_bounds__(256)
void ln_kernel(const void* __restrict__ Xv, const unsigned short* __restrict__ R,
               const float* __restrict__ sc, const float* __restrict__ bi,
               float* __restrict__ outF, unsigned short* __restrict__ outB) {
  const int row = blockIdx.x;
  const int t = threadIdx.x;
  const size_t base = (size_t)row * 1024 + t * 4;
  float4 a;
  if (XF32) {
    a = *(const float4*)((const float*)Xv + base);
  } else {
    const ushort4 xu = *(const ushort4*)((const unsigned short*)Xv + base);
    a.x = bfu(xu.x); a.y = bfu(xu.y); a.z = bfu(xu.z); a.w = bfu(xu.w);
  }
  #pragma unroll
  for (int p = 0; p < NPART; ++p) {
    const ushort4 ru = *(const ushort4*)&R[(size_t)p * 4194304 + base];
    a.x += bfu(ru.x); a.y += bfu(ru.y); a.z += bfu(ru.z); a.w += bfu(ru.w);
  }
  float sum = (a.x + a.y) + (a.z + a.w);
  float sq  = (a.x * a.x + a.y * a.y) + (a.z * a.z + a.w * a.w);
  #pragma unroll
  for (int off = 32; off > 0; off >>= 1) {
    sum += __shfl_down(sum, off);
    sq  += __shfl_down(sq, off);
  }
  __shared__ float s1[4], s2a[4];
  const int wave = t >> 6, lane = t & 63;
  if (lane == 0) { s1[wave] = sum; s2a[wave] = sq; }
  __syncthreads();
  sum = (s1[0] + s1[1]) + (s1[2] + s1[3]);
  sq  = (s2a[0] + s2a[1]) + (s2a[2] + s2a[3]);
  const float mean = sum * (1.f / 1024.f);
  const float var  = sq * (1.f / 1024.f) - mean * mean;
  const float rstd = rsqrtf(var + 1e-5f);
  const float4 s = *(const float4*)&sc[t * 4];
  const float4 bb = *(const float4*)&bi[t * 4];
  float4 y;
  y.x = (a.x - mean) * rstd * s.x + bb.x;
  y.y = (a.y - mean) * rstd * s.y + bb.y;
  y.z = (a.z - mean) * rstd * s.z + bb.z;
  y.w = (a.w - mean) * rstd * s.w + bb.w;
  if (OUTF32) {
    *(float4*)&outF[base] = y;
  } else {
    ushort4 ob; ob.x = f2bf(y.x); ob.y = f2bf(y.y); ob.z = f2bf(y.z); ob.w = f2bf(y.w);
    *(ushort4*)&outB[base] = ob;
  }
}

// ---------- prep: weight transposes (Wq,bq scaled by log2e/8) + x cast + bias concat ----------
__global__ void prep_kernel(const float* __restrict__ Wq, const float* __restrict__ Wk,
                            const float* __restrict__ Wv, const float* __restrict__ Wo,
                            const float* __restrict__ W1, const float* __restrict__ W2,
                            unsigned short* __restrict__ Wqkvt, unsigned short* __restrict__ Wot,
                            unsigned short* __restrict__ W1t, unsigned short* __restrict__ W2t,
                            const float* __restrict__ x, unsigned short* __restrict__ xb,
                            const float* __restrict__ bq, const float* __restrict__ bk,
                            const float* __restrict__ bv, float* __restrict__ bqkv) {
  const int id = blockIdx.x;   // [0,12288) transpose; [12288,16384) cast; [16384,16396) concat
  const int tflat = threadIdx.y * 32 + threadIdx.x;
  if (id >= 16384) {
    const int i = (id - 16384) * 256 + tflat;
    if (i < 1024) bqkv[i] = bq[i] * QSCALE;
    else if (i < 2048) bqkv[i] = bk[i - 1024];
    else if (i < 3072) bqkv[i] = bv[i - 2048];
    return;
  }
  if (id >= 12288) {
    const int i = (id - 12288) * 256 + tflat;   // 1048576 float4s
    const float4 v = ((const float4*)x)[i];
    ushort4 o;
    o.x = f2bf(v.x); o.y = f2bf(v.y); o.z = f2bf(v.z); o.w = f2bf(v.w);
    ((ushort4*)xb)[i] = o;
    return;
  }
  const float* W; unsigned short* Wt; int K, N, tile;
  float scale = 1.f;
  if (id < 4096) {
    const int w = id >> 10; tile = id & 1023; K = 1024; N = 1024;
    if (w == 0)      { W = Wq; Wt = Wqkvt; scale = QSCALE; }
    else if (w == 1) { W = Wk; Wt = Wqkvt + 1024 * 1024; }
    else if (w == 2) { W = Wv; Wt = Wqkvt + 2048 * 1024; }
    else             { W = Wo; Wt = Wot; }
  } else if (id < 8192) { tile = id - 4096; W = W1; Wt = W1t; K = 1024; N = 4096; }
  else                  { tile = id - 8192; W = W2; Wt = W2t; K = 4096; N = 1024; }
  const int tilesX = N >> 5;
  const int bx = (tile & (tilesX - 1)) * 32;
  const int by = (tile / tilesX) * 32;
  __shared__ float tl[32][33];
  const int tx = threadIdx.x, ty = threadIdx.y;
  #pragma unroll
  for (int i = ty; i < 32; i += 8)
    tl[i][tx] = W[(size_t)(by + i) * N + bx + tx];
  __syncthreads();
  #pragma unroll
  for (int i = ty; i < 32; i += 8)
    Wt[(size_t)(bx + i) * K + by + tx] = f2bf(tl[tx][i] * scale);
}

// ---------- launch ----------
extern "C" void kernel_launch(void* const* d_in, const int* in_sizes, int n_in,
                              void* d_out, int out_size, void* d_ws, size_t ws_size,
                              hipStream_t stream) {
  const float* x    = (const float*)d_in[0];
  const float* Wq   = (const float*)d_in[1];
  const float* bq   = (const float*)d_in[2];
  const float* Wk   = (const float*)d_in[3];
  const float* bk   = (const float*)d_in[4];
  const float* Wv   = (const float*)d_in[5];
  const float* bv   = (const float*)d_in[6];
  const float* Wo   = (const float*)d_in[7];
  const float* bo   = (const float*)d_in[8];
  const float* ln1s = (const float*)d_in[9];
  const float* ln1b = (const float*)d_in[10];
  const float* ln2s = (const float*)d_in[11];
  const float* ln2b = (const float*)d_in[12];
  const float* W1   = (const float*)d_in[13];
  const float* b1   = (const float*)d_in[14];
  const float* W2   = (const float*)d_in[15];
  const float* b2   = (const float*)d_in[16];
  float* out = (float*)d_out;

  char* ws = (char*)d_ws;
  const size_t MB = 1u << 20;
  unsigned short* QKVb = (unsigned short*)(ws + 0);
  unsigned short* t1   = (unsigned short*)(ws + 0);
  unsigned short* ffh  = (unsigned short*)(ws + 0);
  unsigned short* Vt   = (unsigned short*)(ws + 32 * MB);
  unsigned short* ff   = (unsigned short*)(ws + 32 * MB);
  unsigned short* xb   = (unsigned short*)(ws + 48 * MB);
  unsigned short* Opart= (unsigned short*)(ws + 48 * MB);
  unsigned short* Wqkvt= (unsigned short*)(ws + 56 * MB);
  float*          Lpart= (float*)(ws + 80 * MB);
  unsigned short* Wot  = (unsigned short*)(ws + 81 * MB);
  unsigned short* W1t  = (unsigned short*)(ws + 83 * MB);
  unsigned short* W2t  = (unsigned short*)(ws + 91 * MB);
  float*          bqkv = (float*)(ws + 99 * MB);
  unsigned short* x1b  = (unsigned short*)(ws + 100 * MB);

  prep_kernel<<<16396, dim3(32, 8), 0, stream>>>(Wq, Wk, Wv, Wo, W1, W2,
                                                 Wqkvt, Wot, W1t, W2t,
                                                 x, xb, bq, bk, bv, bqkv);
  // QKVb = xb @ [Wq*c|Wk|Wv] + b (bf16, 4096x3072); q-section pre-scaled by log2e/8
  gemm256_kernel<1, 0><<<dim3(12, 16, 1), 512, 0, stream>>>(xb, Wqkvt, QKVb, bqkv, 4096, 3072, 1024, 1024);
  // V transpose (32-granular key permutation matched to register-resident P)
  repack_v_kernel<<<1024, 256, 0, stream>>>(QKVb, Vt);
  // flash MFMA attention (barrier-free wave-private LDS), key-split x2 -> bf16 partials
  flash_attn_kernel<<<512, 256, 0, stream>>>(QKVb, Vt, Opart, Lpart);
  // t1{0..1} = normalize(Opart) @ Wo + bo (bf16, split-K x2, combine + invL fused)
  gemm_oproj_kernel<<<dim3(8, 32, 2), 256, 0, stream>>>(Opart, Lpart, Wot, t1, bo);
  // x1b = LN(x + sum t1) (bf16)
  ln_kernel<1, 0, 2><<<4096, 256, 0, stream>>>(x, t1, ln1s, ln1b, nullptr, x1b);
  // ffh = relu(x1b @ W1 + b1) (bf16)
  gemm256_kernel<1, 1><<<dim3(16, 16, 1), 512, 0, stream>>>(x1b, W1t, ffh, b1, 4096, 4096, 1024, 1024);
  // ff{0..3} = ffh @ W2 + b2 (bf16, split-K x4)
  gemm256_kernel<1, 0><<<dim3(4, 16, 4), 512, 0, stream>>>(ffh, W2t, ff, b2, 4096, 1024, 4096, 1024);
  // out = LN(x1b + sum ff) (fp32)
  ln_kernel<0, 1, 4><<<4096, 256, 0, stream>>>(x1b, ff, ln2s, ln2b, out, nullptr);

  (void)in_sizes; (void)n_in; (void)out_size; (void)ws_size;
}

// Round 8
// 333.555 us; speedup vs baseline: 1.0285x; 1.0157x over previous
//
#include <hip/hip_runtime.h>
#include <cstdint>

// ---------- types ----------
typedef __bf16 bf16x8 __attribute__((ext_vector_type(8)));
typedef float  floatx4 __attribute__((ext_vector_type(4)));

__device__ __forceinline__ unsigned short f2bf(float x) {
  union { float f; uint32_t u; } v; v.f = x;
  uint32_t r = (v.u + 0x7FFFu + ((v.u >> 16) & 1u)) >> 16;
  return (unsigned short)r;
}
__device__ __forceinline__ float bflo(uint32_t u) {
  union { uint32_t u; float f; } v; v.u = u << 16; return v.f;
}
__device__ __forceinline__ float bfhi(uint32_t u) {
  union { uint32_t u; float f; } v; v.u = u & 0xffff0000u; return v.f;
}
__device__ __forceinline__ float bfu(unsigned short u) {
  union { uint32_t u; float f; } v; v.u = (uint32_t)u << 16; return v.f;
}

#define QSCALE 0.18033688011f   // log2(e)/8, folded into Wq/bq at prep

// async global->LDS, 16B per lane. LDS dest must be wave-uniform base; HW adds lane*16.
__device__ __forceinline__ void async_copy16(const void* g, void* l) {
  __builtin_amdgcn_global_load_lds(
      (const __attribute__((address_space(1))) uint32_t*)g,
      (__attribute__((address_space(3))) uint32_t*)l, 16, 0, 0);
}

// ---------- bf16 GEMM: C[M,N] = A[M,K] @ Bt[N,K]^T + bias ----------
// 256x256 tile, BK=64, 8 waves (2x4), 8-phase schedule (T2+T3+T4+T5).
// Branch-free steady loop, peeled final iteration, vmcnt(6) at phases 4/8.
// VOUT: blocks with n0>=2048 write the V section directly into Vt in the
// flash-ready [bh*64+d][key-permuted s] layout (replaces repack_v kernel).
// Requires: M,N % 256 == 0, Kper % 128 == 0, Kper >= 256.
template<int OUT_BF16, int RELU, int VOUT>
__global__ __launch_bounds__(512, 2)
void gemm256_kernel(const unsigned short* __restrict__ A,
                    const unsigned short* __restrict__ Bt,
                    void* __restrict__ C, const float* __restrict__ bias,
                    unsigned short* __restrict__ Vt,
                    int M, int N, int K, int Kper) {
  // [buf][half(M/N-half)][128 rows x 64 k], 64KB each -> 128KB total, 1 block/CU
  __shared__ __align__(16) unsigned short lA[2][2][8192];
  __shared__ __align__(16) unsigned short lB[2][2][8192];
  const int tid  = threadIdx.x;
  const int wave = tid >> 6;
  const int lane = tid & 63;

  // XCD-aware swizzle (bijective since nwg % 8 == 0 for all launches here)
  const int gx = gridDim.x, gy = gridDim.y;
  const int nwg = gx * gy;
  int f = blockIdx.y * gx + blockIdx.x;
  f = (f & 7) * (nwg >> 3) + (f >> 3);
  const int m0 = (f % gy) * 256;
  const int n0 = (f / gy) * 256;
  const int kz = blockIdx.z;

  // ----- staging addressing -----
  const int srow = (wave << 3) + (lane >> 3);                 // 0..63
  const int scol = (((lane & 7) ^ ((lane >> 3) & 7)) << 3);   // swizzled ushort col
  const unsigned short* Ab = A  + (size_t)(m0 + srow) * K + kz * Kper + scol;
  const unsigned short* Bb = Bt + (size_t)(n0 + srow) * K + kz * Kper + scol;

  // ----- fragment addressing -----
  const int fr = lane & 15, fq = lane >> 4;
  const int wr = wave >> 2, wc = wave & 3;        // 2x4 wave grid per quadrant
  const int cc0 = ((fq ^ (lane & 7)) << 3);       // k-step 0 chunk (swizzled)
  const int cc1 = cc0 ^ 32;                       // k-step 1 chunk (= ^4 chunks)
  const int arow = (wr * 64 + fr) * 64;
  const int brow = (wc * 32 + fr) * 64;

  floatx4 acc[2][2][4][2];
  #pragma unroll
  for (int i = 0; i < 2; ++i)
    #pragma unroll
    for (int j = 0; j < 2; ++j)
      #pragma unroll
      for (int p = 0; p < 4; ++p)
        #pragma unroll
        for (int q = 0; q < 2; ++q)
          acc[i][j][p][q] = (floatx4){0.f, 0.f, 0.f, 0.f};

  bf16x8 a[4][2], b0[2][2], b1[2][2];

#define STAGE_A(b, h, kt)                                                     \
  do {                                                                        \
    const unsigned short* g_ = Ab + (size_t)((h) * 128) * K + ((size_t)(kt) << 6); \
    async_copy16(g_,                    &lA[b][h][wave << 9]);                \
    async_copy16(g_ + ((size_t)K << 6), &lA[b][h][4096 + (wave << 9)]);       \
  } while (0)
#define STAGE_B(b, h, kt)                                                     \
  do {                                                                        \
    const unsigned short* g_ = Bb + (size_t)((h) * 128) * K + ((size_t)(kt) << 6); \
    async_copy16(g_,                    &lB[b][h][wave << 9]);                \
    async_copy16(g_ + ((size_t)K << 6), &lB[b][h][4096 + (wave << 9)]);       \
  } while (0)
#define RD_A(b, h)                                                            \
  do {                                                                        \
    _Pragma("unroll")                                                         \
    for (int mt = 0; mt < 4; ++mt) {                                          \
      a[mt][0] = *(const bf16x8*)&lA[b][h][arow + mt * 1024 + cc0];           \
      a[mt][1] = *(const bf16x8*)&lA[b][h][arow + mt * 1024 + cc1];           \
    }                                                                         \
  } while (0)
#define RD_B(b, h, BB)                                                        \
  do {                                                                        \
    _Pragma("unroll")                                                         \
    for (int nt = 0; nt < 2; ++nt) {                                          \
      BB[nt][0] = *(const bf16x8*)&lB[b][h][brow + nt * 1024 + cc0];          \
      BB[nt][1] = *(const bf16x8*)&lB[b][h][brow + nt * 1024 + cc1];          \
    }                                                                         \
  } while (0)
#define MMAQ(mq, nq, BB)                                                      \
  do {                                                                        \
    __builtin_amdgcn_s_setprio(1);                                            \
    _Pragma("unroll")                                                         \
    for (int s = 0; s < 2; ++s)                                               \
      _Pragma("unroll")                                                       \
      for (int mt = 0; mt < 4; ++mt)                                          \
        _Pragma("unroll")                                                     \
        for (int nt = 0; nt < 2; ++nt)                                        \
          acc[mq][nq][mt][nt] = __builtin_amdgcn_mfma_f32_16x16x32_bf16(      \
              a[mt][s], BB[nt][s], acc[mq][nq][mt][nt], 0, 0, 0);             \
    __builtin_amdgcn_s_setprio(0);                                            \
  } while (0)
#define BARRIER() __builtin_amdgcn_s_barrier()
#define LGKM0()   asm volatile("s_waitcnt lgkmcnt(0)" ::: "memory")
#define LGKM8()   asm volatile("s_waitcnt lgkmcnt(8)" ::: "memory")

  const int T = Kper >> 6;   // K-tiles (even, >=4 for our shapes)

  // prologue: tile0 (all 4 halves) + tile1 (3 halves); wait all of tile0.
  STAGE_A(0, 0, 0); STAGE_B(0, 0, 0); STAGE_B(0, 1, 0); STAGE_A(0, 1, 0);
  STAGE_A(1, 0, 1); STAGE_B(1, 0, 1); STAGE_B(1, 1, 1);
  asm volatile("s_waitcnt vmcnt(6)" ::: "memory");
  BARRIER();

  #pragma unroll 1
  for (int it = 0; it < (T >> 1) - 1; ++it) {
    const int t0 = it << 1;
    // ---- tile t0 (buf0) ----
    RD_A(0, 0); RD_B(0, 0, b0);
    STAGE_A(1, 1, t0 + 1);
    LGKM8();
    BARRIER(); LGKM0();
    MMAQ(0, 0, b0);
    BARRIER();
    RD_B(0, 1, b1);
    STAGE_A(0, 0, t0 + 2);
    BARRIER(); LGKM0();
    MMAQ(0, 1, b1);
    BARRIER();
    RD_A(0, 1);
    STAGE_B(0, 0, t0 + 2);
    BARRIER(); LGKM0();
    MMAQ(1, 0, b0);
    BARRIER();
    STAGE_B(0, 1, t0 + 2);
    asm volatile("s_waitcnt vmcnt(6)" ::: "memory");
    BARRIER();
    MMAQ(1, 1, b1);
    BARRIER();
    // ---- tile t0+1 (buf1) ----
    RD_A(1, 0); RD_B(1, 0, b0);
    STAGE_A(0, 1, t0 + 2);
    LGKM8();
    BARRIER(); LGKM0();
    MMAQ(0, 0, b0);
    BARRIER();
    RD_B(1, 1, b1);
    STAGE_A(1, 0, t0 + 3);
    BARRIER(); LGKM0();
    MMAQ(0, 1, b1);
    BARRIER();
    RD_A(1, 1);
    STAGE_B(1, 0, t0 + 3);
    BARRIER(); LGKM0();
    MMAQ(1, 0, b0);
    BARRIER();
    STAGE_B(1, 1, t0 + 3);
    asm volatile("s_waitcnt vmcnt(6)" ::: "memory");
    BARRIER();
    MMAQ(1, 1, b1);
    BARRIER();
  }

  // ---- peeled tail: tiles T-2 (buf0) and T-1 (buf1) ----
  RD_A(0, 0); RD_B(0, 0, b0);
  STAGE_A(1, 1, T - 1);
  MMAQ(0, 0, b0);
  RD_B(0, 1, b1);
  MMAQ(0, 1, b1);
  RD_A(0, 1);
  MMAQ(1, 0, b0);
  MMAQ(1, 1, b1);
  asm volatile("s_waitcnt vmcnt(0)" ::: "memory");
  BARRIER();
  RD_A(1, 0); RD_B(1, 0, b0);
  MMAQ(0, 0, b0);
  RD_B(1, 1, b1);
  MMAQ(0, 1, b1);
  RD_A(1, 1);
  MMAQ(1, 0, b0);
  MMAQ(1, 1, b1);
#undef STAGE_A
#undef STAGE_B
#undef RD_A
#undef RD_B
#undef MMAQ
#undef BARRIER
#undef LGKM0
#undef LGKM8

  // epilogue
  const float* bp = (kz == 0) ? bias : nullptr;
  if (VOUT && n0 >= 2048) {
    // V section -> Vt[(b*16+h)*64 + d][key-permuted s], 8B/thread contiguous.
    // perm within 32-key blocks: position p holds key k(p) with
    // k0k1=p0p1, k2k3=p3p4, k4=p2  =>  p(k) = (k&3)|((k>>4&1)<<2)|((k>>2&3)<<3).
    #pragma unroll
    for (int mq = 0; mq < 2; ++mq)
      #pragma unroll
      for (int nq = 0; nq < 2; ++nq)
        #pragma unroll
        for (int mt = 0; mt < 4; ++mt)
          #pragma unroll
          for (int nt = 0; nt < 2; ++nt) {
            const int gn = n0 + nq * 128 + wc * 32 + nt * 16 + fr;
            const int dd = gn - 2048;                  // h*64 + d
            const float bv = bp ? bp[gn] : 0.f;
            const int gm0r = m0 + mq * 128 + wr * 64 + mt * 16 + fq * 4;
            const int b_ = gm0r >> 11, s0 = gm0r & 2047;   // s0 bits0-1 == 0
            const int pbase = (((s0 >> 4) & 1) << 2) | (((s0 >> 2) & 3) << 3);
            const size_t vrow = (size_t)(b_ * 16 + (dd >> 6)) * 64 + (dd & 63);
            ushort4 o;
            o.x = f2bf(acc[mq][nq][mt][nt][0] + bv);
            o.y = f2bf(acc[mq][nq][mt][nt][1] + bv);
            o.z = f2bf(acc[mq][nq][mt][nt][2] + bv);
            o.w = f2bf(acc[mq][nq][mt][nt][3] + bv);
            *(ushort4*)&Vt[vrow * 2048 + (s0 & ~31) + pbase] = o;
          }
    return;
  }
  char* Cz = (char*)C + (size_t)kz * M * N * (OUT_BF16 ? 2 : 4);
  #pragma unroll
  for (int mq = 0; mq < 2; ++mq)
    #pragma unroll
    for (int nq = 0; nq < 2; ++nq)
      #pragma unroll
      for (int mt = 0; mt < 4; ++mt)
        #pragma unroll
        for (int nt = 0; nt < 2; ++nt) {
          const int gn = n0 + nq * 128 + wc * 32 + nt * 16 + fr;
          const float bv = bp ? bp[gn] : 0.f;
          #pragma unroll
          for (int r = 0; r < 4; ++r) {
            const int gm = m0 + mq * 128 + wr * 64 + mt * 16 + fq * 4 + r;
            float v = acc[mq][nq][mt][nt][r] + bv;
            if (RELU) v = fmaxf(v, 0.f);
            if (OUT_BF16) ((unsigned short*)Cz)[(size_t)gm * N + gn] = f2bf(v);
            else          ((float*)Cz)[(size_t)gm * N + gn] = v;
          }
        }
}

// ---------- O-proj GEMM with FUSED attention-combine + invL in the A-staging ----------
// A[gm][c] = (Opart0 + Opart1)[row(gm,c)] * rcp(L0+L1)[row(gm,c)], row = (b*16+h)*2048+q.
// M=4096,N=1024,K=1024, split-K 2 (Kper=512). bf16 out.
__global__ __launch_bounds__(256, 2)
void gemm_oproj_kernel(const unsigned short* __restrict__ Opart,
                       const float* __restrict__ Lpart,
                       const unsigned short* __restrict__ Bt,
                       unsigned short* __restrict__ C,
                       const float* __restrict__ bias) {
  const int K = 1024, N = 1024, M = 4096, Kper = 512;
  __shared__ __align__(16) unsigned short lA[128 * 32];
  __shared__ __align__(16) unsigned short lB[128 * 32];
  const int tid  = threadIdx.x;
  const int wave = tid >> 6;
  const int lane = tid & 63;

  const int gx = gridDim.x, gy = gridDim.y;
  int flat = blockIdx.y * gx + blockIdx.x;
  const int per = (gx * gy) >> 3;
  flat = (flat & 7) * per + (flat >> 3);
  const int sq = flat >> 6, inner = flat & 63;
  const int sqm = gy >> 3;
  const int m0 = ((sq % sqm) * 8 + (inner & 7)) * 128;
  const int n0 = ((sq / sqm) * 8 + (inner >> 3)) * 128;

  const int kz = blockIdx.z;
  const int wm = (wave >> 1) * 64;
  const int wn = (wave & 1) * 64;
  const int sa_row = lane >> 2;
  const int sa_k   = ((lane & 3) ^ ((lane >> 3) & 3)) * 8;
  const int fr = lane & 15;
  const int fq = lane >> 4;
  const int sw = (fr >> 1) & 3;

  const int r0 = (wave * 2 + 0) * 16 + sa_row;
  const int r1 = (wave * 2 + 1) * 16 + sa_row;
  const int gm0 = m0 + r0, gm1 = m0 + r1;
  const int base0 = (gm0 >> 11) * 16 * 2048 + (gm0 & 2047);   // (b*16)*2048 + q
  const int base1 = (gm1 >> 11) * 16 * 2048 + (gm1 & 2047);
  const unsigned short* B0 = Bt + (size_t)(n0 + r0) * K + kz * Kper + sa_k;
  const unsigned short* B1 = Bt + (size_t)(n0 + r1) * K + kz * Kper + sa_k;
  const int c0 = (wave * 2 + 0) * 512;
  const int c1 = (wave * 2 + 1) * 512;

  floatx4 acc[4][4];
  #pragma unroll
  for (int i = 0; i < 4; ++i)
    #pragma unroll
    for (int j = 0; j < 4; ++j)
      acc[i][j] = (floatx4){0.f, 0.f, 0.f, 0.f};

  for (int kt = 0; kt < 16; ++kt) {
    __syncthreads();
    const int kk = kz * Kper + (kt << 5) + sa_k;   // global k index (h*64 + d)
    const int h = kk >> 6, d0 = kk & 63;
    #pragma unroll
    for (int j = 0; j < 2; ++j) {
      const int base = j ? base1 : base0;
      const int cj   = j ? c1 : c0;
      const int rowi = base + h * 2048;
      const size_t idx = (size_t)rowi * 64 + d0;
      const uint4 a = *(const uint4*)(Opart + idx);
      const uint4 b = *(const uint4*)(Opart + idx + 4194304);   // + 65536*64
      const float s = __builtin_amdgcn_rcpf(Lpart[rowi] + Lpart[rowi + 65536]);
      const uint32_t au[4] = {a.x, a.y, a.z, a.w};
      const uint32_t bu[4] = {b.x, b.y, b.z, b.w};
      uint32_t w[4];
      #pragma unroll
      for (int k = 0; k < 4; ++k) {
        const float lo = (bflo(au[k]) + bflo(bu[k])) * s;
        const float hi = (bfhi(au[k]) + bfhi(bu[k])) * s;
        w[k] = (uint32_t)f2bf(lo) | ((uint32_t)f2bf(hi) << 16);
      }
      uint4 wv; wv.x = w[0]; wv.y = w[1]; wv.z = w[2]; wv.w = w[3];
      *(uint4*)&lA[cj + lane * 8] = wv;
    }
    async_copy16(B0 + (kt << 5), &lB[c0]);
    async_copy16(B1 + (kt << 5), &lB[c1]);
    __syncthreads();

    bf16x8 af[4], bf[4];
    #pragma unroll
    for (int t = 0; t < 4; ++t) {
      af[t] = *(const bf16x8*)&lA[(wm + t * 16 + fr) * 32 + (fq ^ sw) * 8];
      bf[t] = *(const bf16x8*)&lB[(wn + t * 16 + fr) * 32 + (fq ^ sw) * 8];
    }
    #pragma unroll
    for (int mt = 0; mt < 4; ++mt)
      #pragma unroll
      for (int nt = 0; nt < 4; ++nt)
        acc[mt][nt] = __builtin_amdgcn_mfma_f32_16x16x32_bf16(af[mt], bf[nt], acc[mt][nt], 0, 0, 0);
  }

  const float* bp = (kz == 0) ? bias : nullptr;
  unsigned short* Cz = C + (size_t)kz * M * N;
  #pragma unroll
  for (int mt = 0; mt < 4; ++mt) {
    #pragma unroll
    for (int nt = 0; nt < 4; ++nt) {
      const int gn = n0 + wn + nt * 16 + fr;
      const float bv = bp ? bp[gn] : 0.f;
      #pragma unroll
      for (int r = 0; r < 4; ++r) {
        const int gm = m0 + wm + mt * 16 + fq * 4 + r;
        Cz[(size_t)gm * N + gn] = f2bf(acc[mt][nt][r] + bv);
      }
    }
  }
}

// ---------- flash attention: wave-private LDS + T15 double-pipeline ----------
// Grid 512 = ksp(2) x b(2) x h(16) x qtile(8), XCD-chunked. 4 waves x 64 q;
// each wave double-buffers its own K/V half-tile via global_load_lds ->
// ZERO barriers, counted vmcnt(8). T15: QK^T of tile t+1 is issued BEFORE
// softmax+PV of tile t (two live score states sA/sB + stage-local V frags),
// so QK MFMAs overlap exp2/cvt VALU. Swapped QK^T keeps P register-resident
// (V key-permuted to match); row sums via ones-column MFMA.
// Writes UNNORMALIZED bf16 Opart [ksp][bh*2048+q][64] and fp32 Lpart.
__global__ __launch_bounds__(256, 2)
void flash_attn_kernel(const unsigned short* __restrict__ QKVb,
                       const unsigned short* __restrict__ Vt,
                       unsigned short* __restrict__ Opart, float* __restrict__ Lpart) {
  const int bid0 = blockIdx.x;               // 512 blocks
  const int lb = (bid0 & 7) * 64 + (bid0 >> 3);   // XCD-chunked remap (bijective)
  const int qt = lb & 7, h = (lb >> 3) & 15, b = (lb >> 7) & 1, ksp = lb >> 8;
  const int bh = b * 16 + h;
  const int wave = threadIdx.x >> 6, lane = threadIdx.x & 63;
  const int fr = lane & 15, fq = lane >> 4;

  __shared__ __align__(16) unsigned short lK[4][2][32 * 64];  // [wave][buf], 4KB each
  __shared__ __align__(16) unsigned short lV[4][2][64 * 32];  // [wave][buf], 4KB each

  const int q_base = qt * 256 + wave * 64;

  // Q fragments: 64 q per wave, resident (faithful no-transpose q view).
  bf16x8 aq[4][2];
  #pragma unroll
  for (int g = 0; g < 4; ++g) {
    const int s2 = q_base + g * 16 + fr;
    const unsigned short* qp = QKVb + (size_t)(b * 2048 + h * 128 + (s2 >> 4)) * 3072
                             + (s2 & 15) * 64 + fq * 8;
    aq[g][0] = *(const bf16x8*)qp;
    aq[g][1] = *(const bf16x8*)(qp + 32);
  }

  floatx4 o_acc[4][4], l_acc[4];
  #pragma unroll
  for (int g = 0; g < 4; ++g) {
    l_acc[g] = (floatx4){0.f, 0.f, 0.f, 0.f};
    #pragma unroll
    for (int nt = 0; nt < 4; ++nt) o_acc[g][nt] = (floatx4){0.f, 0.f, 0.f, 0.f};
  }

  const unsigned short* Kg = QKVb + 1024 + h * 64;
  const unsigned short* Vg = Vt + (size_t)bh * 64 * 2048;

  // staging addresses (wave stages its WHOLE half-tile: 4 K-rows-of-8 + 4 V-rows-of-16)
  const unsigned short* Ksrc = Kg + (size_t)(b * 2048 + (lane >> 3)) * 3072
                             + ((lane & 7) ^ (lane >> 3)) * 8;
  const unsigned short* Vsrc = Vg + (size_t)(lane >> 2) * 2048
                             + ((lane & 3) ^ ((lane >> 3) & 3)) * 8;

  auto pref = [&](int key0, int bi) {
    #pragma unroll
    for (int i = 0; i < 4; ++i)
      async_copy16(Ksrc + (size_t)(key0 + i * 8) * 3072, (char*)&lK[wave][bi][0] + i * 1024);
    #pragma unroll
    for (int i = 0; i < 4; ++i)
      async_copy16(Vsrc + (size_t)(i * 16) * 2048 + key0, (char*)&lV[wave][bi][0] + i * 1024);
  };

  const int swk = fr & 7;
  const int swv = (fr >> 1) & 3;

  bf16x8 bk[2][2], bvA[4], bvB[4];
  floatx4 sA[4][2], sB[4][2];
  bf16x8 ones;
  #pragma unroll
  for (int j = 0; j < 8; ++j) ones[j] = (__bf16)1.0f;

#define RDF(bi, BV)                                                           \
  do {                                                                        \
    const unsigned short* LK = &lK[wave][bi][0];                              \
    const unsigned short* LV = &lV[wave][bi][0];                              \
    bk[0][0] = *(const bf16x8*)&LK[(fr) * 64      + ((0 + fq) ^ swk) * 8];    \
    bk[0][1] = *(const bf16x8*)&LK[(fr) * 64      + ((4 + fq) ^ swk) * 8];    \
    bk[1][0] = *(const bf16x8*)&LK[(16 + fr) * 64 + ((0 + fq) ^ swk) * 8];    \
    bk[1][1] = *(const bf16x8*)&LK[(16 + fr) * 64 + ((4 + fq) ^ swk) * 8];    \
    BV[0] = *(const bf16x8*)&LV[(fr) * 32      + (fq ^ swv) * 8];             \
    BV[1] = *(const bf16x8*)&LV[(16 + fr) * 32 + (fq ^ swv) * 8];             \
    BV[2] = *(const bf16x8*)&LV[(32 + fr) * 32 + (fq ^ swv) * 8];             \
    BV[3] = *(const bf16x8*)&LV[(48 + fr) * 32 + (fq ^ swv) * 8];             \
  } while (0)

#define QKALL(S)                                                              \
  do {                                                                        \
    __builtin_amdgcn_s_setprio(1);                                            \
    _Pragma("unroll")                                                         \
    for (int g = 0; g < 4; ++g) {                                             \
      floatx4 z0 = (floatx4){0.f, 0.f, 0.f, 0.f};                             \
      floatx4 z1 = (floatx4){0.f, 0.f, 0.f, 0.f};                             \
      z0 = __builtin_amdgcn_mfma_f32_16x16x32_bf16(bk[0][0], aq[g][0], z0, 0, 0, 0); \
      z0 = __builtin_amdgcn_mfma_f32_16x16x32_bf16(bk[0][1], aq[g][1], z0, 0, 0, 0); \
      z1 = __builtin_amdgcn_mfma_f32_16x16x32_bf16(bk[1][0], aq[g][0], z1, 0, 0, 0); \
      z1 = __builtin_amdgcn_mfma_f32_16x16x32_bf16(bk[1][1], aq[g][1], z1, 0, 0, 0); \
      S[g][0] = z0; S[g][1] = z1;                                             \
    }                                                                         \
    __builtin_amdgcn_s_setprio(0);                                            \
  } while (0)

#define SMPV(S, BV)                                                           \
  do {                                                                        \
    _Pragma("unroll")                                                         \
    for (int g = 0; g < 4; ++g) {                                             \
      float p[8];                                                             \
      _Pragma("unroll")                                                       \
      for (int r = 0; r < 4; ++r) {                                           \
        p[r]     = __builtin_amdgcn_exp2f(S[g][0][r]);                        \
        p[4 + r] = __builtin_amdgcn_exp2f(S[g][1][r]);                        \
      }                                                                       \
      bf16x8 ap;                                                              \
      _Pragma("unroll")                                                       \
      for (int j = 0; j < 8; ++j) ap[j] = (__bf16)p[j];                       \
      __builtin_amdgcn_s_setprio(1);                                          \
      _Pragma("unroll")                                                       \
      for (int nt = 0; nt < 4; ++nt)                                          \
        o_acc[g][nt] = __builtin_amdgcn_mfma_f32_16x16x32_bf16(ap, BV[nt], o_acc[g][nt], 0, 0, 0); \
      l_acc[g] = __builtin_amdgcn_mfma_f32_16x16x32_bf16(ap, ones, l_acc[g], 0, 0, 0); \
      __builtin_amdgcn_s_setprio(0);                                          \
    }                                                                         \
  } while (0)
#define VM8()   asm volatile("s_waitcnt vmcnt(8)" ::: "memory")
#define VM0()   asm volatile("s_waitcnt vmcnt(0)" ::: "memory")
#define LGKM0() asm volatile("s_waitcnt lgkmcnt(0)" ::: "memory")

  const int key00 = ksp * 1024;
  // prologue: tile0 -> buf0, QK(tile0); tile1 loading into buf1.
  pref(key00, 0);                                   // 8 out
  VM0();
  RDF(0, bvA); LGKM0();
  QKALL(sA);                                        // tile 0
  pref(key00 + 32, 1);                              // 8 out
  #pragma unroll 1
  for (int hh = 0; hh < 30; hh += 2) {
    pref(key00 + (hh + 2) * 32, 0);                 // 16 out (buf0 frags consumed)
    VM8();                                          // buf1 (tile hh+1) ready
    RDF(1, bvB); LGKM0();
    QKALL(sB);                                      // QK of tile hh+1 ...
    SMPV(sA, bvA);                                  // ... overlaps SM+PV of tile hh
    pref(key00 + (hh + 3) * 32, 1);                 // 16 out
    VM8();                                          // buf0 (tile hh+2) ready
    RDF(0, bvA); LGKM0();
    QKALL(sA);                                      // tile hh+2
    SMPV(sB, bvB);                                  // tile hh+1
  }
  // exit: sA = tile 30 (bvA); buf1 loading tile 31 (8 out).
  VM0();
  RDF(1, bvB); LGKM0();
  QKALL(sB);                                        // tile 31
  SMPV(sA, bvA);                                    // tile 30
  SMPV(sB, bvB);                                    // tile 31
#undef RDF
#undef QKALL
#undef SMPV
#undef VM8
#undef VM0
#undef LGKM0

  // epilogue: unnormalized bf16 partials + fp32 row sums.
  const size_t rbase = (size_t)ksp * 65536 + (size_t)bh * 2048 + q_base;
  #pragma unroll
  for (int g = 0; g < 4; ++g) {
    #pragma unroll
    for (int r = 0; r < 4; ++r)
      if (fr == 0) Lpart[rbase + g * 16 + fq * 4 + r] = l_acc[g][r];
    #pragma unroll
    for (int nt = 0; nt < 4; ++nt)
      #pragma unroll
      for (int r = 0; r < 4; ++r)
        Opart[(rbase + g * 16 + fq * 4 + r) * 64 + nt * 16 + fr] = f2bf(o_acc[g][nt][r]);
  }
}

// ---------- layernorm: LN(X + sum of NPART bf16 partials) ----------
template<int XF32, int OUTF32, int NPART>
__global__ __launch_bounds__(256)
void ln_kernel(const void* __restrict__ Xv, const unsigned short* __restrict__ R,
               const float* __restrict__ sc, const float* __restrict__ bi,
               float* __restrict__ outF, unsigned short* __restrict__ outB) {
  const int row = blockIdx.x;
  const int t = threadIdx.x;
  const size_t base = (size_t)row * 1024 + t * 4;
  float4 a;
  if (XF32) {
    a = *(const float4*)((const float*)Xv + base);
  } else {
    const ushort4 xu = *(const ushort4*)((const unsigned short*)Xv + base);
    a.x = bfu(xu.x); a.y = bfu(xu.y); a.z = bfu(xu.z); a.w = bfu(xu.w);
  }
  #pragma unroll
  for (int p = 0; p < NPART; ++p) {
    const ushort4 ru = *(const ushort4*)&R[(size_t)p * 4194304 + base];
    a.x += bfu(ru.x); a.y += bfu(ru.y); a.z += bfu(ru.z); a.w += bfu(ru.w);
  }
  float sum = (a.x + a.y) + (a.z + a.w);
  float sq  = (a.x * a.x + a.y * a.y) + (a.z * a.z + a.w * a.w);
  #pragma unroll
  for (int off = 32; off > 0; off >>= 1) {
    sum += __shfl_down(sum, off);
    sq  += __shfl_down(sq, off);
  }
  __shared__ float s1[4], s2a[4];
  const int wave = t >> 6, lane = t & 63;
  if (lane == 0) { s1[wave] = sum; s2a[wave] = sq; }
  __syncthreads();
  sum = (s1[0] + s1[1]) + (s1[2] + s1[3]);
  sq  = (s2a[0] + s2a[1]) + (s2a[2] + s2a[3]);
  const float mean = sum * (1.f / 1024.f);
  const float var  = sq * (1.f / 1024.f) - mean * mean;
  const float rstd = rsqrtf(var + 1e-5f);
  const float4 s = *(const float4*)&sc[t * 4];
  const float4 bb = *(const float4*)&bi[t * 4];
  float4 y;
  y.x = (a.x - mean) * rstd * s.x + bb.x;
  y.y = (a.y - mean) * rstd * s.y + bb.y;
  y.z = (a.z - mean) * rstd * s.z + bb.z;
  y.w = (a.w - mean) * rstd * s.w + bb.w;
  if (OUTF32) {
    *(float4*)&outF[base] = y;
  } else {
    ushort4 ob; ob.x = f2bf(y.x); ob.y = f2bf(y.y); ob.z = f2bf(y.z); ob.w = f2bf(y.w);
    *(ushort4*)&outB[base] = ob;
  }
}

// ---------- prep: weight transposes (Wq,bq scaled by log2e/8) + x cast + bias concat ----------
__global__ void prep_kernel(const float* __restrict__ Wq, const float* __restrict__ Wk,
                            const float* __restrict__ Wv, const float* __restrict__ Wo,
                            const float* __restrict__ W1, const float* __restrict__ W2,
                            unsigned short* __restrict__ Wqkvt, unsigned short* __restrict__ Wot,
                            unsigned short* __restrict__ W1t, unsigned short* __restrict__ W2t,
                            const float* __restrict__ x, unsigned short* __restrict__ xb,
                            const float* __restrict__ bq, const float* __restrict__ bk,
                            const float* __restrict__ bv, float* __restrict__ bqkv) {
  const int id = blockIdx.x;   // [0,12288) transpose; [12288,16384) cast; [16384,16396) concat
  const int tflat = threadIdx.y * 32 + threadIdx.x;
  if (id >= 16384) {
    const int i = (id - 16384) * 256 + tflat;
    if (i < 1024) bqkv[i] = bq[i] * QSCALE;
    else if (i < 2048) bqkv[i] = bk[i - 1024];
    else if (i < 3072) bqkv[i] = bv[i - 2048];
    return;
  }
  if (id >= 12288) {
    const int i = (id - 12288) * 256 + tflat;   // 1048576 float4s
    const float4 v = ((const float4*)x)[i];
    ushort4 o;
    o.x = f2bf(v.x); o.y = f2bf(v.y); o.z = f2bf(v.z); o.w = f2bf(v.w);
    ((ushort4*)xb)[i] = o;
    return;
  }
  const float* W; unsigned short* Wt; int K, N, tile;
  float scale = 1.f;
  if (id < 4096) {
    const int w = id >> 10; tile = id & 1023; K = 1024; N = 1024;
    if (w == 0)      { W = Wq; Wt = Wqkvt; scale = QSCALE; }
    else if (w == 1) { W = Wk; Wt = Wqkvt + 1024 * 1024; }
    else if (w == 2) { W = Wv; Wt = Wqkvt + 2048 * 1024; }
    else             { W = Wo; Wt = Wot; }
  } else if (id < 8192) { tile = id - 4096; W = W1; Wt = W1t; K = 1024; N = 4096; }
  else                  { tile = id - 8192; W = W2; Wt = W2t; K = 4096; N = 1024; }
  const int tilesX = N >> 5;
  const int bx = (tile & (tilesX - 1)) * 32;
  const int by = (tile / tilesX) * 32;
  __shared__ float tl[32][33];
  const int tx = threadIdx.x, ty = threadIdx.y;
  #pragma unroll
  for (int i = ty; i < 32; i += 8)
    tl[i][tx] = W[(size_t)(by + i) * N + bx + tx];
  __syncthreads();
  #pragma unroll
  for (int i = ty; i < 32; i += 8)
    Wt[(size_t)(bx + i) * K + by + tx] = f2bf(tl[tx][i] * scale);
}

// ---------- launch ----------
extern "C" void kernel_launch(void* const* d_in, const int* in_sizes, int n_in,
                              void* d_out, int out_size, void* d_ws, size_t ws_size,
                              hipStream_t stream) {
  const float* x    = (const float*)d_in[0];
  const float* Wq   = (const float*)d_in[1];
  const float* bq   = (const float*)d_in[2];
  const float* Wk   = (const float*)d_in[3];
  const float* bk   = (const float*)d_in[4];
  const float* Wv   = (const float*)d_in[5];
  const float* bv   = (const float*)d_in[6];
  const float* Wo   = (const float*)d_in[7];
  const float* bo   = (const float*)d_in[8];
  const float* ln1s = (const float*)d_in[9];
  const float* ln1b = (const float*)d_in[10];
  const float* ln2s = (const float*)d_in[11];
  const float* ln2b = (const float*)d_in[12];
  const float* W1   = (const float*)d_in[13];
  const float* b1   = (const float*)d_in[14];
  const float* W2   = (const float*)d_in[15];
  const float* b2   = (const float*)d_in[16];
  float* out = (float*)d_out;

  char* ws = (char*)d_ws;
  const size_t MB = 1u << 20;
  unsigned short* QKVb = (unsigned short*)(ws + 0);
  unsigned short* t1   = (unsigned short*)(ws + 0);
  unsigned short* ffh  = (unsigned short*)(ws + 0);
  unsigned short* Vt   = (unsigned short*)(ws + 32 * MB);
  unsigned short* ff   = (unsigned short*)(ws + 32 * MB);
  unsigned short* xb   = (unsigned short*)(ws + 48 * MB);
  unsigned short* Opart= (unsigned short*)(ws + 48 * MB);
  unsigned short* Wqkvt= (unsigned short*)(ws + 56 * MB);
  float*          Lpart= (float*)(ws + 80 * MB);
  unsigned short* Wot  = (unsigned short*)(ws + 81 * MB);
  unsigned short* W1t  = (unsigned short*)(ws + 83 * MB);
  unsigned short* W2t  = (unsigned short*)(ws + 91 * MB);
  float*          bqkv = (float*)(ws + 99 * MB);
  unsigned short* x1b  = (unsigned short*)(ws + 100 * MB);

  prep_kernel<<<16396, dim3(32, 8), 0, stream>>>(Wq, Wk, Wv, Wo, W1, W2,
                                                 Wqkvt, Wot, W1t, W2t,
                                                 x, xb, bq, bk, bv, bqkv);
  // QKVb = xb @ [Wq*c|Wk|Wv] + b; V section written DIRECTLY into Vt (permuted)
  gemm256_kernel<1, 0, 1><<<dim3(12, 16, 1), 512, 0, stream>>>(xb, Wqkvt, QKVb, bqkv, Vt, 4096, 3072, 1024, 1024);
  // flash MFMA attention (wave-private LDS + T15 pipeline), key-split x2 -> bf16 partials
  flash_attn_kernel<<<512, 256, 0, stream>>>(QKVb, Vt, Opart, Lpart);
  // t1{0..1} = normalize(Opart) @ Wo + bo (bf16, split-K x2, combine + invL fused)
  gemm_oproj_kernel<<<dim3(8, 32, 2), 256, 0, stream>>>(Opart, Lpart, Wot, t1, bo);
  // x1b = LN(x + sum t1) (bf16)
  ln_kernel<1, 0, 2><<<4096, 256, 0, stream>>>(x, t1, ln1s, ln1b, nullptr, x1b);
  // ffh = relu(x1b @ W1 + b1) (bf16)
  gemm256_kernel<1, 1, 0><<<dim3(16, 16, 1), 512, 0, stream>>>(x1b, W1t, ffh, b1, nullptr, 4096, 4096, 1024, 1024);
  // ff{0..3} = ffh @ W2 + b2 (bf16, split-K x4)
  gemm256_kernel<1, 0, 0><<<dim3(4, 16, 4), 512, 0, stream>>>(ffh, W2t, ff, b2, nullptr, 4096, 1024, 4096, 1024);
  // out = LN(x1b + sum ff) (fp32)
  ln_kernel<0, 1, 4><<<4096, 256, 0, stream>>>(x1b, ff, ln2s, ln2b, out, nullptr);

  (void)in_sizes; (void)n_in; (void)out_size; (void)ws_size;
}